// Round 9
// baseline (382.260 us; speedup 1.0000x reference)
//
#include <hip/hip_runtime.h>

#define N_NODES  100000
#define N_EDGES  2000000
#define N_GRAPHS 1000
#define NFEAT    7
#define BN_EPS   1e-5f
#define MAXDEG   64    // in-degree ~ Poisson(20); P(max over 100k > 63) < 1e-9

#define BSH      7     // 128-node dst buckets
#define NBKT     782   // ceil(100000/128)
#define BCAP     3584  // per-bucket edge cap: mean 2560 + 20 sigma
#define E_PER_BLK 4096

// bf16 helpers (storage only; all arithmetic fp32)
__device__ __forceinline__ unsigned bf16_rne(float f) {
  unsigned u = __float_as_uint(f);
  return (u + 0x7FFFu + ((u >> 16) & 1u)) >> 16;
}
__device__ __forceinline__ float bf_lo(unsigned u) { return __uint_as_float(u << 16); }
__device__ __forceinline__ float bf_hi(unsigned u) { return __uint_as_float(u & 0xFFFF0000u); }

// ---------------- b1: bucket edges by dst>>7, block-contiguous writes ----------------
__global__ __launch_bounds__(1024) void b1_bucket(const int* __restrict__ src,
                                                  const int* __restrict__ dst,
                                                  int* __restrict__ gCur,
                                                  unsigned* __restrict__ ebuf) {
  __shared__ int hist[NBKT], base[NBKT];
  int tid = threadIdx.x;
  for (int i = tid; i < NBKT; i += 1024) hist[i] = 0;
  __syncthreads();
  unsigned pk[4];
  int bo[4];
  int e0 = blockIdx.x * E_PER_BLK;
#pragma unroll
  for (int k = 0; k < 4; ++k) {
    int e = e0 + k * 1024 + tid;
    if (e < N_EDGES) {
      int d = dst[e], s = src[e];
      int b = d >> BSH;
      int off = atomicAdd(&hist[b], 1);
      pk[k] = ((unsigned)(d & 127) << 17) | (unsigned)s;
      bo[k] = (b << 17) | off;
    } else {
      bo[k] = -1;
    }
  }
  __syncthreads();
  for (int i = tid; i < NBKT; i += 1024)
    base[i] = hist[i] ? atomicAdd(&gCur[i], hist[i]) : 0;
  __syncthreads();
#pragma unroll
  for (int k = 0; k < 4; ++k) {
    if (bo[k] >= 0) {
      int b = bo[k] >> 17, off = bo[k] & 0x1FFFF;
      int p = base[b] + off;
      if (p < BCAP) ebuf[(size_t)b * BCAP + p] = pk[k];
    }
  }
}

// ---------------- b2: one block per bucket -> padded csr + cnt ----------------
__global__ __launch_bounds__(512) void b2_csr(const unsigned* __restrict__ ebuf,
                                              const int* __restrict__ gCnt,
                                              int* __restrict__ cnt,
                                              int* __restrict__ csr) {
  __shared__ int hist[128];
  __shared__ int stage[128 * MAXDEG];
  int b = blockIdx.x, tid = threadIdx.x;
  if (tid < 128) hist[tid] = 0;
  __syncthreads();
  int n = gCnt[b];
  if (n > BCAP) n = BCAP;
  const unsigned* eb = ebuf + (size_t)b * BCAP;
  for (int i = tid; i < n; i += 512) {
    unsigned pk = eb[i];
    int dloc = (int)(pk >> 17);
    int slot = atomicAdd(&hist[dloc], 1);
    if (slot < MAXDEG) stage[(dloc << 6) + slot] = (int)(pk & 0x1FFFFu);
  }
  __syncthreads();
  if (tid < 128) {
    int gnode = (b << BSH) + tid;
    if (gnode < N_NODES) cnt[gnode] = hist[tid];
  }
  const int4* st4 = (const int4*)stage;
  int4* dst4 = (int4*)(csr + (size_t)b * (128 * MAXDEG));
  for (int i = tid; i < 128 * MAXDEG / 4; i += 512) dst4[i] = st4[i];
}

// ---------------- xcvt: x (fp32 [N,7]) -> xc (bf16 [N,8], pad dim7 = 0) ----------------
__global__ __launch_bounds__(256) void xcvt_kernel(const float* __restrict__ x,
                                                   unsigned* __restrict__ xc) {
  int i = blockIdx.x * 256 + threadIdx.x;
  if (i >= N_NODES * 4) return;
  int n = i >> 2, p = i & 3;
  float lo = x[n * 7 + 2 * p];
  float hi = (2 * p + 1 < 7) ? x[n * 7 + 2 * p + 1] : 0.f;
  xc[i] = bf16_rne(lo) | (bf16_rne(hi) << 16);
}

// ---------------- conv1: node-PAIR cooperative-row gather (proven R1/R2) ----------------
__global__ __launch_bounds__(256) void gin1(
    const unsigned short* __restrict__ xc16, const int* __restrict__ cnt,
    const int* __restrict__ csr,
    const float* __restrict__ W1, const float* __restrict__ b1,
    const float* __restrict__ W2, const float* __restrict__ b2,
    const float* __restrict__ gamma, const float* __restrict__ beta,
    const float* __restrict__ mean, const float* __restrict__ var,
    unsigned short* __restrict__ hout16) {
  __shared__ __align__(16) float zsA[4][8], zsB[4][8];
  __shared__ __align__(16) float tsA[4][32], tsB[4][32];
  int tid = threadIdx.x;
  int w = __builtin_amdgcn_readfirstlane(tid >> 6);
  int lane = tid & 63;
  int grp = lane >> 2;   // row group (16 rows per gather step)
  int ch  = lane & 3;    // 4-byte chunk = dims [2ch, 2ch+1]
  int half = lane >> 5, j = lane & 31;  // MLP roles

  float wr1[4], wr2[16];
#pragma unroll
  for (int i = 0; i < 4; ++i) {
    int k = half * 4 + i;
    wr1[i] = (k < 7) ? W1[k * 32 + j] : 0.f;
  }
#pragma unroll
  for (int i = 0; i < 16; ++i) wr2[i] = W2[(half * 16 + i) * 32 + j];
  float vb1 = b1[j], vb2 = b2[j];
  float sc = gamma[j] * rsqrtf(var[j] + BN_EPS);
  float sh = beta[j] - mean[j] * sc;

  const unsigned* xc32 = (const unsigned*)xc16;  // 4 x unsigned per 16-B row

  const int NW = gridDim.x * 4;
  const int NPAIR = N_NODES / 2;
  for (int pr = blockIdx.x * 4 + w; pr < NPAIR; pr += NW) {
    int n0 = 2 * pr, n1 = n0 + 1;
    int d0 = cnt[n0];
    int d1 = cnt[n1];
    if (d0 > 63) d0 = 63;
    if (d1 > 63) d1 = 63;
    int dE0 = d0 + 1, dE1 = d1 + 1;

    int idx0 = (lane < d0) ? csr[n0 * MAXDEG + lane] : n0;
    int idx1 = (lane < d1) ? csr[n1 * MAXDEG + lane] : n1;

    unsigned vA[4], vB[4];
#pragma unroll
    for (int s = 0; s < 4; ++s) {
      int sidA = __shfl(idx0, s * 16 + grp);
      vA[s] = xc32[(size_t)sidA * 4 + ch];
    }
#pragma unroll
    for (int s = 0; s < 4; ++s) {
      int sidB = __shfl(idx1, s * 16 + grp);
      vB[s] = xc32[(size_t)sidB * 4 + ch];
    }

    float a0 = 0.f, a1 = 0.f;   // node0
    float c0 = 0.f, c1 = 0.f;   // node1
#pragma unroll
    for (int s = 0; s < 4; ++s) {
      int e = s * 16 + grp;
      if (e < dE0) { a0 += bf_lo(vA[s]); a1 += bf_hi(vA[s]); }
      if (e < dE1) { c0 += bf_lo(vB[s]); c1 += bf_hi(vB[s]); }
    }
#pragma unroll
    for (int m = 4; m <= 32; m <<= 1) {
      a0 += __shfl_xor(a0, m); a1 += __shfl_xor(a1, m);
      c0 += __shfl_xor(c0, m); c1 += __shfl_xor(c1, m);
    }
    if (grp == 0) {  // lanes 0..3 deposit dims [2ch, 2ch+1]
      float2 za = {a0, a1};
      float2 zc = {c0, c1};
      *(float2*)&zsA[w][ch * 2] = za;
      *(float2*)&zsB[w][ch * 2] = zc;
    }

    // ---- MLP node0 ----
    float tp = half ? 0.f : vb1;
    {
      const float4* zp = (const float4*)&zsA[w][half * 4];
      float4 z0 = zp[0];
      tp = fmaf(z0.x, wr1[0], tp); tp = fmaf(z0.y, wr1[1], tp);
      tp = fmaf(z0.z, wr1[2], tp); tp = fmaf(z0.w, wr1[3], tp);
    }
    tp += __shfl_xor(tp, 32);
    tp = fmaxf(tp, 0.f);
    if (!half) tsA[w][j] = tp;

    float op = half ? 0.f : vb2;
    {
      const float4* tpp = (const float4*)&tsA[w][half * 16];
      float4 t0 = tpp[0], t1 = tpp[1], t2 = tpp[2], t3 = tpp[3];
      op = fmaf(t0.x, wr2[0], op);  op = fmaf(t0.y, wr2[1], op);
      op = fmaf(t0.z, wr2[2], op);  op = fmaf(t0.w, wr2[3], op);
      op = fmaf(t1.x, wr2[4], op);  op = fmaf(t1.y, wr2[5], op);
      op = fmaf(t1.z, wr2[6], op);  op = fmaf(t1.w, wr2[7], op);
      op = fmaf(t2.x, wr2[8], op);  op = fmaf(t2.y, wr2[9], op);
      op = fmaf(t2.z, wr2[10], op); op = fmaf(t2.w, wr2[11], op);
      op = fmaf(t3.x, wr2[12], op); op = fmaf(t3.y, wr2[13], op);
      op = fmaf(t3.z, wr2[14], op); op = fmaf(t3.w, wr2[15], op);
    }
    op += __shfl_xor(op, 32);
    if (!half) {
      op = fmaxf(op, 0.f) * sc + sh;
      float hi = __shfl(op, j | 1);
      if ((j & 1) == 0) {
        unsigned pk = bf16_rne(op) | (bf16_rne(hi) << 16);
        ((unsigned*)hout16)[n0 * 16 + (j >> 1)] = pk;
      }
    }

    // ---- MLP node1 ----
    float tq = half ? 0.f : vb1;
    {
      const float4* zp = (const float4*)&zsB[w][half * 4];
      float4 z0 = zp[0];
      tq = fmaf(z0.x, wr1[0], tq); tq = fmaf(z0.y, wr1[1], tq);
      tq = fmaf(z0.z, wr1[2], tq); tq = fmaf(z0.w, wr1[3], tq);
    }
    tq += __shfl_xor(tq, 32);
    tq = fmaxf(tq, 0.f);
    if (!half) tsB[w][j] = tq;

    float oq = half ? 0.f : vb2;
    {
      const float4* tpp = (const float4*)&tsB[w][half * 16];
      float4 t0 = tpp[0], t1 = tpp[1], t2 = tpp[2], t3 = tpp[3];
      oq = fmaf(t0.x, wr2[0], oq);  oq = fmaf(t0.y, wr2[1], oq);
      oq = fmaf(t0.z, wr2[2], oq);  oq = fmaf(t0.w, wr2[3], oq);
      oq = fmaf(t1.x, wr2[4], oq);  oq = fmaf(t1.y, wr2[5], oq);
      oq = fmaf(t1.z, wr2[6], oq);  oq = fmaf(t1.w, wr2[7], oq);
      oq = fmaf(t2.x, wr2[8], oq);  oq = fmaf(t2.y, wr2[9], oq);
      oq = fmaf(t2.z, wr2[10], oq); oq = fmaf(t2.w, wr2[11], oq);
      oq = fmaf(t3.x, wr2[12], oq); oq = fmaf(t3.y, wr2[13], oq);
      oq = fmaf(t3.z, wr2[14], oq); oq = fmaf(t3.w, wr2[15], oq);
    }
    oq += __shfl_xor(oq, 32);
    if (!half) {
      oq = fmaxf(oq, 0.f) * sc + sh;
      float hi = __shfl(oq, j | 1);
      if ((j & 1) == 0) {
        unsigned pk = bf16_rne(oq) | (bf16_rne(hi) << 16);
        ((unsigned*)hout16)[n1 * 16 + (j >> 1)] = pk;
      }
    }
  }
}

// ---------------- conv2..5: pair gather, full 1-deep pipeline (R8) ----------------
// Distance-2 P-stage (cnt+csr), distance-1 G-stage (gather into wA/wB),
// compute from vA/vB; rotation w->v by register copy (compile-time indices).
// Coverage: pair k gets P at iter k-2, G at iter k-1, compute at iter k.
__global__ __launch_bounds__(256) void gin_layer32(
    const unsigned short* __restrict__ hin16, const int* __restrict__ cnt,
    const int* __restrict__ csr,
    const float* __restrict__ W1, const float* __restrict__ b1,
    const float* __restrict__ W2, const float* __restrict__ b2,
    const float* __restrict__ gamma, const float* __restrict__ beta,
    const float* __restrict__ mean, const float* __restrict__ var,
    unsigned short* __restrict__ hout16) {
  __shared__ __align__(16) float zsA[4][32], tsA[4][32];
  __shared__ __align__(16) float zsB[4][32], tsB[4][32];
  int tid = threadIdx.x;
  int w = __builtin_amdgcn_readfirstlane(tid >> 6);  // wave id, force-scalar
  int lane = tid & 63;
  int grp = lane >> 3;   // row group within a gather step
  int ch  = lane & 7;    // 8-byte chunk = dims [4ch, 4ch+3]
  int half = lane >> 5, j = lane & 31;  // MLP roles

  float wr1[16], wr2[16];
#pragma unroll
  for (int i = 0; i < 16; ++i) wr1[i] = W1[(half * 16 + i) * 32 + j];
#pragma unroll
  for (int i = 0; i < 16; ++i) wr2[i] = W2[(half * 16 + i) * 32 + j];
  float vb1 = b1[j], vb2 = b2[j];
  float sc = gamma[j] * rsqrtf(var[j] + BN_EPS);
  float sh = beta[j] - mean[j] * sc;

  const int NW = gridDim.x * 4;
  const int NPAIR = N_NODES / 2;  // 50000

  // ---- prologue: P(cur) + G(cur) + P(next) ----
  int pr = blockIdx.x * 4 + w;   // < 8192 < NPAIR always
  int d0, d1, idx0, idx1;
  {
    int n0 = 2 * pr, n1 = n0 + 1;
    d0 = cnt[n0]; d1 = cnt[n1];
    if (d0 > 63) d0 = 63;
    if (d1 > 63) d1 = 63;
    idx0 = (lane < d0) ? csr[n0 * MAXDEG + lane] : n0;
    idx1 = (lane < d1) ? csr[n1 * MAXDEG + lane] : n1;
  }
  uint2 vA[8], vB[8];
#pragma unroll
  for (int s = 0; s < 8; ++s) {
    int sid = __shfl(idx0, s * 8 + grp);
    vA[s] = *(const uint2*)(hin16 + (size_t)sid * 32 + ch * 4);
  }
#pragma unroll
  for (int s = 0; s < 8; ++s) {
    int sid = __shfl(idx1, s * 8 + grp);
    vB[s] = *(const uint2*)(hin16 + (size_t)sid * 32 + ch * 4);
  }
  int prn = pr + NW;
  bool hasN = prn < NPAIR;
  int dn0 = 0, dn1 = 0, in0 = 0, in1 = 0;
  if (hasN) {
    int m0 = 2 * prn, m1 = m0 + 1;
    dn0 = cnt[m0]; dn1 = cnt[m1];
    if (dn0 > 63) dn0 = 63;
    if (dn1 > 63) dn1 = 63;
    in0 = (lane < dn0) ? csr[m0 * MAXDEG + lane] : m0;
    in1 = (lane < dn1) ? csr[m1 * MAXDEG + lane] : m1;
  }

  while (true) {
    // ---- issue G(next) into w-regs (idx returned during previous compute) ----
    uint2 wA[8], wB[8];
    if (hasN) {
#pragma unroll
      for (int s = 0; s < 8; ++s) {
        int sid = __shfl(in0, s * 8 + grp);
        wA[s] = *(const uint2*)(hin16 + (size_t)sid * 32 + ch * 4);
      }
#pragma unroll
      for (int s = 0; s < 8; ++s) {
        int sid = __shfl(in1, s * 8 + grp);
        wB[s] = *(const uint2*)(hin16 + (size_t)sid * 32 + ch * 4);
      }
    }
    // ---- issue P(next2) ----
    int prn2 = prn + NW;
    bool hasN2 = hasN && (prn2 < NPAIR);
    int dn20 = 0, dn21 = 0, in20 = 0, in21 = 0;
    if (hasN2) {
      int m0 = 2 * prn2, m1 = m0 + 1;
      dn20 = cnt[m0]; dn21 = cnt[m1];
      if (dn20 > 63) dn20 = 63;
      if (dn21 > 63) dn21 = 63;
      in20 = (lane < dn20) ? csr[m0 * MAXDEG + lane] : m0;
      in21 = (lane < dn21) ? csr[m1 * MAXDEG + lane] : m1;
    }

    // ---- compute current pair from v-regs ----
    int n0 = 2 * pr, n1 = n0 + 1;
    int dE0 = d0 + 1, dE1 = d1 + 1;  // + self rows
    float a0 = 0.f, a1 = 0.f, a2 = 0.f, a3 = 0.f;
    float c0 = 0.f, c1 = 0.f, c2 = 0.f, c3 = 0.f;
#pragma unroll
    for (int s = 0; s < 8; ++s) {
      int e = s * 8 + grp;
      if (e < dE0) {
        a0 += bf_lo(vA[s].x); a1 += bf_hi(vA[s].x);
        a2 += bf_lo(vA[s].y); a3 += bf_hi(vA[s].y);
      }
      if (e < dE1) {
        c0 += bf_lo(vB[s].x); c1 += bf_hi(vB[s].x);
        c2 += bf_lo(vB[s].y); c3 += bf_hi(vB[s].y);
      }
    }
#pragma unroll
    for (int m = 8; m <= 32; m <<= 1) {
      a0 += __shfl_xor(a0, m); a1 += __shfl_xor(a1, m);
      a2 += __shfl_xor(a2, m); a3 += __shfl_xor(a3, m);
      c0 += __shfl_xor(c0, m); c1 += __shfl_xor(c1, m);
      c2 += __shfl_xor(c2, m); c3 += __shfl_xor(c3, m);
    }
    if (grp == 0) {
      float4 za = {a0, a1, a2, a3};
      float4 zc = {c0, c1, c2, c3};
      *(float4*)&zsA[w][ch * 4] = za;
      *(float4*)&zsB[w][ch * 4] = zc;
    }

    // ---- MLP node0 ----
    float tp = half ? 0.f : vb1;
    {
      const float4* zp = (const float4*)&zsA[w][half * 16];
      float4 q0 = zp[0], q1 = zp[1], q2 = zp[2], q3 = zp[3];
      tp = fmaf(q0.x, wr1[0], tp);  tp = fmaf(q0.y, wr1[1], tp);
      tp = fmaf(q0.z, wr1[2], tp);  tp = fmaf(q0.w, wr1[3], tp);
      tp = fmaf(q1.x, wr1[4], tp);  tp = fmaf(q1.y, wr1[5], tp);
      tp = fmaf(q1.z, wr1[6], tp);  tp = fmaf(q1.w, wr1[7], tp);
      tp = fmaf(q2.x, wr1[8], tp);  tp = fmaf(q2.y, wr1[9], tp);
      tp = fmaf(q2.z, wr1[10], tp); tp = fmaf(q2.w, wr1[11], tp);
      tp = fmaf(q3.x, wr1[12], tp); tp = fmaf(q3.y, wr1[13], tp);
      tp = fmaf(q3.z, wr1[14], tp); tp = fmaf(q3.w, wr1[15], tp);
    }
    tp += __shfl_xor(tp, 32);
    tp = fmaxf(tp, 0.f);
    if (!half) tsA[w][j] = tp;

    float op = half ? 0.f : vb2;
    {
      const float4* tpp = (const float4*)&tsA[w][half * 16];
      float4 q0 = tpp[0], q1 = tpp[1], q2 = tpp[2], q3 = tpp[3];
      op = fmaf(q0.x, wr2[0], op);  op = fmaf(q0.y, wr2[1], op);
      op = fmaf(q0.z, wr2[2], op);  op = fmaf(q0.w, wr2[3], op);
      op = fmaf(q1.x, wr2[4], op);  op = fmaf(q1.y, wr2[5], op);
      op = fmaf(q1.z, wr2[6], op);  op = fmaf(q1.w, wr2[7], op);
      op = fmaf(q2.x, wr2[8], op);  op = fmaf(q2.y, wr2[9], op);
      op = fmaf(q2.z, wr2[10], op); op = fmaf(q2.w, wr2[11], op);
      op = fmaf(q3.x, wr2[12], op); op = fmaf(q3.y, wr2[13], op);
      op = fmaf(q3.z, wr2[14], op); op = fmaf(q3.w, wr2[15], op);
    }
    op += __shfl_xor(op, 32);
    if (!half) {
      op = fmaxf(op, 0.f) * sc + sh;
      float hi = __shfl(op, j | 1);
      if ((j & 1) == 0) {
        unsigned pk = bf16_rne(op) | (bf16_rne(hi) << 16);
        ((unsigned*)hout16)[n0 * 16 + (j >> 1)] = pk;
      }
    }

    // ---- MLP node1 ----
    float tq = half ? 0.f : vb1;
    {
      const float4* zp = (const float4*)&zsB[w][half * 16];
      float4 q0 = zp[0], q1 = zp[1], q2 = zp[2], q3 = zp[3];
      tq = fmaf(q0.x, wr1[0], tq);  tq = fmaf(q0.y, wr1[1], tq);
      tq = fmaf(q0.z, wr1[2], tq);  tq = fmaf(q0.w, wr1[3], tq);
      tq = fmaf(q1.x, wr1[4], tq);  tq = fmaf(q1.y, wr1[5], tq);
      tq = fmaf(q1.z, wr1[6], tq);  tq = fmaf(q1.w, wr1[7], tq);
      tq = fmaf(q2.x, wr1[8], tq);  tq = fmaf(q2.y, wr1[9], tq);
      tq = fmaf(q2.z, wr1[10], tq); tq = fmaf(q2.w, wr1[11], tq);
      tq = fmaf(q3.x, wr1[12], tq); tq = fmaf(q3.y, wr1[13], tq);
      tq = fmaf(q3.z, wr1[14], tq); tq = fmaf(q3.w, wr1[15], tq);
    }
    tq += __shfl_xor(tq, 32);
    tq = fmaxf(tq, 0.f);
    if (!half) tsB[w][j] = tq;

    float oq = half ? 0.f : vb2;
    {
      const float4* tpp = (const float4*)&tsB[w][half * 16];
      float4 q0 = tpp[0], q1 = tpp[1], q2 = tpp[2], q3 = tpp[3];
      oq = fmaf(q0.x, wr2[0], oq);  oq = fmaf(q0.y, wr2[1], oq);
      oq = fmaf(q0.z, wr2[2], oq);  oq = fmaf(q0.w, wr2[3], oq);
      oq = fmaf(q1.x, wr2[4], oq);  oq = fmaf(q1.y, wr2[5], oq);
      oq = fmaf(q1.z, wr2[6], oq);  oq = fmaf(q1.w, wr2[7], oq);
      oq = fmaf(q2.x, wr2[8], oq);  oq = fmaf(q2.y, wr2[9], oq);
      oq = fmaf(q2.z, wr2[10], oq); oq = fmaf(q2.w, wr2[11], oq);
      oq = fmaf(q3.x, wr2[12], oq); oq = fmaf(q3.y, wr2[13], oq);
      oq = fmaf(q3.z, wr2[14], oq); oq = fmaf(q3.w, wr2[15], oq);
    }
    oq += __shfl_xor(oq, 32);
    if (!half) {
      oq = fmaxf(oq, 0.f) * sc + sh;
      float hi = __shfl(oq, j | 1);
      if ((j & 1) == 0) {
        unsigned pk = bf16_rne(oq) | (bf16_rne(hi) << 16);
        ((unsigned*)hout16)[n1 * 16 + (j >> 1)] = pk;
      }
    }

    // ---- rotate pipeline state ----
    if (!hasN) break;
    pr = prn;
    d0 = dn0; d1 = dn1;
#pragma unroll
    for (int s = 0; s < 8; ++s) { vA[s] = wA[s]; vB[s] = wB[s]; }
    prn = prn2; hasN = hasN2;
    dn0 = dn20; dn1 = dn21; in0 = in20; in1 = in21;
  }
}

// ---------------- pool: one block per graph (batch sorted), bf16 in ----------------
__global__ __launch_bounds__(256) void pool_kernel(const unsigned short* __restrict__ h16,
                                                   const int* __restrict__ batch,
                                                   float* __restrict__ g) {
  __shared__ int s_lo, s_hi;
  __shared__ float red[8][33];
  int gr = blockIdx.x;
  if (threadIdx.x == 0) {
    int lo = 0, hi = N_NODES;
    while (lo < hi) { int m = (lo + hi) >> 1; if (batch[m] < gr) lo = m + 1; else hi = m; }
    s_lo = lo;
  } else if (threadIdx.x == 1) {
    int lo = 0, hi = N_NODES;
    while (lo < hi) { int m = (lo + hi) >> 1; if (batch[m] < gr + 1) lo = m + 1; else hi = m; }
    s_hi = lo;
  }
  __syncthreads();
  int lo = s_lo, hi = s_hi;
  int j = threadIdx.x & 31;
  int nd = threadIdx.x >> 5;
  float acc = 0.f;
  for (int n = lo + nd; n < hi; n += 8)
    acc += __uint_as_float((unsigned)h16[n * 32 + j] << 16);
  red[nd][j] = acc;
  __syncthreads();
  if (threadIdx.x < 32) {
    float s = 0.f;
#pragma unroll
    for (int r = 0; r < 8; ++r) s += red[r][j];
    g[gr * 32 + j] = s;
  }
}

// ---------------- head (fp32) ----------------
__global__ __launch_bounds__(256) void head_kernel(
    const float* __restrict__ g, const float* __restrict__ W1, const float* __restrict__ b1,
    const float* __restrict__ W2, const float* __restrict__ b2, float* __restrict__ out) {
  __shared__ float sW1[1024], sb1[32];
  __shared__ float sW2[64], sb2[2];
  __shared__ float zb[8][33], tb[8][33], lb[8][2];
  int tid = threadIdx.x;
  for (int i = tid; i < 1024; i += 256) sW1[i] = W1[i];
  if (tid < 64) sW2[tid] = W2[tid];
  if (tid < 32) sb1[tid] = b1[tid];
  if (tid < 2) sb2[tid] = b2[tid];
  int nd = tid >> 5;
  int gr = blockIdx.x * 8 + nd;
  int j = tid & 31;
  __syncthreads();
  float z = (gr < N_GRAPHS) ? g[gr * 32 + j] : 0.f;
  zb[nd][j] = z;
  __syncthreads();
  float t = sb1[j];
#pragma unroll
  for (int k = 0; k < 32; ++k) t = fmaf(zb[nd][k], sW1[k * 32 + j], t);
  t = fmaxf(t, 0.f);
  tb[nd][j] = t;
  __syncthreads();
  if (j < 2) {
    float l = sb2[j];
#pragma unroll
    for (int k = 0; k < 32; ++k) l = fmaf(tb[nd][k], sW2[k * 2 + j], l);
    lb[nd][j] = l;
  }
  __syncthreads();
  if (gr < N_GRAPHS && j < 2) {
    float l0 = lb[nd][0], l1 = lb[nd][1];
    float m = fmaxf(l0, l1);
    float lse = m + logf(expf(l0 - m) + expf(l1 - m));
    out[gr * 2 + j] = lb[nd][j] - lse;
  }
}

extern "C" void kernel_launch(void* const* d_in, const int* in_sizes, int n_in,
                              void* d_out, int out_size, void* d_ws, size_t ws_size,
                              hipStream_t stream) {
  const float* x     = (const float*)d_in[0];
  const int*   eidx  = (const int*)d_in[1];
  const int*   batch = (const int*)d_in[2];
  const float* c1W1  = (const float*)d_in[3];
  const float* c1b1  = (const float*)d_in[4];
  const float* c1W2  = (const float*)d_in[5];
  const float* c1b2  = (const float*)d_in[6];
  const float* csW1  = (const float*)d_in[7];
  const float* csb1  = (const float*)d_in[8];
  const float* csW2  = (const float*)d_in[9];
  const float* csb2  = (const float*)d_in[10];
  const float* bng   = (const float*)d_in[11];
  const float* bnb   = (const float*)d_in[12];
  const float* bnm   = (const float*)d_in[13];
  const float* bnv   = (const float*)d_in[14];
  const float* fc1W  = (const float*)d_in[15];
  const float* fc1b  = (const float*)d_in[16];
  const float* fc2W  = (const float*)d_in[17];
  const float* fc2b  = (const float*)d_in[18];
  float* out = (float*)d_out;

  const int* src = eidx;
  const int* dst = eidx + N_EDGES;

  // workspace (~50.2 MB)
  char* p = (char*)d_ws;
  unsigned short* hA16 = (unsigned short*)p; p += (size_t)N_NODES * 32 * 2;   // 6.4 MB
  unsigned short* hB16 = (unsigned short*)p; p += (size_t)N_NODES * 32 * 2;   // 6.4 MB
  int*      cnt  = (int*)p;      p += (size_t)N_NODES * 4;                    // 0.4 MB
  int*      csr  = (int*)p;      p += (size_t)NBKT * 128 * MAXDEG * 4;        // 25.6 MB
  unsigned* ebuf = (unsigned*)p; p += (size_t)NBKT * BCAP * 4;                // 11.2 MB
  int*      gCur = (int*)p;      p += 1024 * 4;
  float*    g    = (float*)p;    p += (size_t)N_GRAPHS * 32 * 4;
  // xc (bf16 [N,8], 1.6 MB) aliases ebuf: ebuf is dead after b2_csr completes
  unsigned* xc = ebuf;

  // ---- build: bucket pass + per-bucket padded-CSR pass ----
  (void)hipMemsetAsync(gCur, 0, 1024 * 4, stream);
  b1_bucket<<<(N_EDGES + E_PER_BLK - 1) / E_PER_BLK, 1024, 0, stream>>>(src, dst, gCur, ebuf);
  b2_csr<<<NBKT, 512, 0, stream>>>(ebuf, gCur, cnt, csr);

  // ---- x -> bf16 padded rows (after b2: xc aliases ebuf) ----
  xcvt_kernel<<<(N_NODES * 4 + 255) / 256, 256, 0, stream>>>(x, xc);

  // ---- conv1 (7->32) + relu + bn0 ----
  gin1<<<2048, 256, 0, stream>>>(
      (const unsigned short*)xc, cnt, csr, c1W1, c1b1, c1W2, c1b2,
      bng, bnb, bnm, bnv, hA16);

  // ---- conv2..5 (32->32) + relu + bn1..4, 1-deep gather pipeline ----
  unsigned short* cur = hA16;
  unsigned short* nxt = hB16;
  for (int i = 0; i < 4; ++i) {
    gin_layer32<<<2048, 256, 0, stream>>>(
        cur, cnt, csr,
        csW1 + (size_t)i * 1024, csb1 + (size_t)i * 32,
        csW2 + (size_t)i * 1024, csb2 + (size_t)i * 32,
        bng + (size_t)(i + 1) * 32, bnb + (size_t)(i + 1) * 32,
        bnm + (size_t)(i + 1) * 32, bnv + (size_t)(i + 1) * 32, nxt);
    unsigned short* tmp = cur; cur = nxt; nxt = tmp;
  }

  pool_kernel<<<N_GRAPHS, 256, 0, stream>>>(cur, batch, g);
  head_kernel<<<(N_GRAPHS + 7) / 8, 256, 0, stream>>>(g, fc1W, fc1b, fc2W, fc2b, out);
}

// Round 10
// 342.945 us; speedup vs baseline: 1.1146x; 1.1146x over previous
//
#include <hip/hip_runtime.h>

#define N_NODES  100000
#define N_EDGES  2000000
#define N_GRAPHS 1000
#define NFEAT    7
#define BN_EPS   1e-5f
#define MAXDEG   64    // in-degree ~ Poisson(20); P(max over 100k > 63) < 1e-9

#define BSH      7     // 128-node dst buckets
#define NBKT     782   // ceil(100000/128)
#define BCAP     3584  // per-bucket edge cap: mean 2560 + 20 sigma
#define E_PER_BLK 4096
#define NGRP     6250  // 100000/16 node groups

// bf16 helpers (storage only; all arithmetic fp32)
__device__ __forceinline__ unsigned bf16_rne(float f) {
  unsigned u = __float_as_uint(f);
  return (u + 0x7FFFu + ((u >> 16) & 1u)) >> 16;
}
__device__ __forceinline__ float bf_lo(unsigned u) { return __uint_as_float(u << 16); }
__device__ __forceinline__ float bf_hi(unsigned u) { return __uint_as_float(u & 0xFFFF0000u); }

// ---------------- b1: bucket edges by dst>>7, block-contiguous writes ----------------
__global__ __launch_bounds__(1024) void b1_bucket(const int* __restrict__ src,
                                                  const int* __restrict__ dst,
                                                  int* __restrict__ gCur,
                                                  unsigned* __restrict__ ebuf) {
  __shared__ int hist[NBKT], base[NBKT];
  int tid = threadIdx.x;
  for (int i = tid; i < NBKT; i += 1024) hist[i] = 0;
  __syncthreads();
  unsigned pk[4];
  int bo[4];
  int e0 = blockIdx.x * E_PER_BLK;
#pragma unroll
  for (int k = 0; k < 4; ++k) {
    int e = e0 + k * 1024 + tid;
    if (e < N_EDGES) {
      int d = dst[e], s = src[e];
      int b = d >> BSH;
      int off = atomicAdd(&hist[b], 1);
      pk[k] = ((unsigned)(d & 127) << 17) | (unsigned)s;
      bo[k] = (b << 17) | off;
    } else {
      bo[k] = -1;
    }
  }
  __syncthreads();
  for (int i = tid; i < NBKT; i += 1024)
    base[i] = hist[i] ? atomicAdd(&gCur[i], hist[i]) : 0;
  __syncthreads();
#pragma unroll
  for (int k = 0; k < 4; ++k) {
    if (bo[k] >= 0) {
      int b = bo[k] >> 17, off = bo[k] & 0x1FFFF;
      int p = base[b] + off;
      if (p < BCAP) ebuf[(size_t)b * BCAP + p] = pk[k];
    }
  }
}

// ---------------- b2: one block per bucket -> padded csr (pad=self) + cnt + gmax ----------------
__global__ __launch_bounds__(512) void b2_csr(const unsigned* __restrict__ ebuf,
                                              const int* __restrict__ gCnt,
                                              int* __restrict__ cnt,
                                              int* __restrict__ csr,
                                              int* __restrict__ gmax) {
  __shared__ int hist[128];
  __shared__ int stage[128 * MAXDEG];
  int b = blockIdx.x, tid = threadIdx.x;
  if (tid < 128) hist[tid] = 0;
  // init stage to self-node id: pad slots become valid self rows, and slot
  // cnt (first un-filled) supplies the GIN self term.
  for (int i = tid; i < 128 * MAXDEG; i += 512) stage[i] = (b << BSH) + (i >> 6);
  __syncthreads();
  int n = gCnt[b];
  if (n > BCAP) n = BCAP;
  const unsigned* eb = ebuf + (size_t)b * BCAP;
  for (int i = tid; i < n; i += 512) {
    unsigned pk = eb[i];
    int dloc = (int)(pk >> 17);
    int slot = atomicAdd(&hist[dloc], 1);
    if (slot < MAXDEG) stage[(dloc << 6) + slot] = (int)(pk & 0x1FFFFu);
  }
  __syncthreads();
  if (tid < 128) {
    int gnode = (b << BSH) + tid;
    if (gnode < N_NODES) cnt[gnode] = hist[tid];
  }
  if (tid < 8) {  // per-16-node-group max effective degree (dE = min(d,63)+1)
    int mx = 1;
#pragma unroll
    for (int k = 0; k < 16; ++k) {
      int d = hist[tid * 16 + k];
      if (d > 63) d = 63;
      if (d + 1 > mx) mx = d + 1;
    }
    gmax[(b << 3) + tid] = mx;
  }
  const int4* st4 = (const int4*)stage;
  int4* dst4 = (int4*)(csr + (size_t)b * (128 * MAXDEG));
  for (int i = tid; i < 128 * MAXDEG / 4; i += 512) dst4[i] = st4[i];
}

// ---------------- xcvt: x (fp32 [N,7]) -> xc (bf16 [N,8], pad dim7 = 0) ----------------
__global__ __launch_bounds__(256) void xcvt_kernel(const float* __restrict__ x,
                                                   unsigned* __restrict__ xc) {
  int i = blockIdx.x * 256 + threadIdx.x;
  if (i >= N_NODES * 4) return;
  int n = i >> 2, p = i & 3;
  float lo = x[n * 7 + 2 * p];
  float hi = (2 * p + 1 < 7) ? x[n * 7 + 2 * p + 1] : 0.f;
  xc[i] = bf16_rne(lo) | (bf16_rne(hi) << 16);
}

// ---------------- conv1: node-PAIR cooperative-row gather (proven R1/R2) ----------------
// NOTE: pad slots in csr now hold the self id, so the (lane<d0 ? csr : n0)
// select still yields exactly the same indices as before.
__global__ __launch_bounds__(256) void gin1(
    const unsigned short* __restrict__ xc16, const int* __restrict__ cnt,
    const int* __restrict__ csr,
    const float* __restrict__ W1, const float* __restrict__ b1,
    const float* __restrict__ W2, const float* __restrict__ b2,
    const float* __restrict__ gamma, const float* __restrict__ beta,
    const float* __restrict__ mean, const float* __restrict__ var,
    unsigned short* __restrict__ hout16) {
  __shared__ __align__(16) float zsA[4][8], zsB[4][8];
  __shared__ __align__(16) float tsA[4][32], tsB[4][32];
  int tid = threadIdx.x;
  int w = __builtin_amdgcn_readfirstlane(tid >> 6);
  int lane = tid & 63;
  int grp = lane >> 2;   // row group (16 rows per gather step)
  int ch  = lane & 3;    // 4-byte chunk = dims [2ch, 2ch+1]
  int half = lane >> 5, j = lane & 31;  // MLP roles

  float wr1[4], wr2[16];
#pragma unroll
  for (int i = 0; i < 4; ++i) {
    int k = half * 4 + i;
    wr1[i] = (k < 7) ? W1[k * 32 + j] : 0.f;
  }
#pragma unroll
  for (int i = 0; i < 16; ++i) wr2[i] = W2[(half * 16 + i) * 32 + j];
  float vb1 = b1[j], vb2 = b2[j];
  float sc = gamma[j] * rsqrtf(var[j] + BN_EPS);
  float sh = beta[j] - mean[j] * sc;

  const unsigned* xc32 = (const unsigned*)xc16;  // 4 x unsigned per 16-B row

  const int NW = gridDim.x * 4;
  const int NPAIR = N_NODES / 2;
  for (int pr = blockIdx.x * 4 + w; pr < NPAIR; pr += NW) {
    int n0 = 2 * pr, n1 = n0 + 1;
    int d0 = cnt[n0];
    int d1 = cnt[n1];
    if (d0 > 63) d0 = 63;
    if (d1 > 63) d1 = 63;
    int dE0 = d0 + 1, dE1 = d1 + 1;

    int idx0 = (lane < d0) ? csr[n0 * MAXDEG + lane] : n0;
    int idx1 = (lane < d1) ? csr[n1 * MAXDEG + lane] : n1;

    unsigned vA[4], vB[4];
#pragma unroll
    for (int s = 0; s < 4; ++s) {
      int sidA = __shfl(idx0, s * 16 + grp);
      vA[s] = xc32[(size_t)sidA * 4 + ch];
    }
#pragma unroll
    for (int s = 0; s < 4; ++s) {
      int sidB = __shfl(idx1, s * 16 + grp);
      vB[s] = xc32[(size_t)sidB * 4 + ch];
    }

    float a0 = 0.f, a1 = 0.f;   // node0
    float c0 = 0.f, c1 = 0.f;   // node1
#pragma unroll
    for (int s = 0; s < 4; ++s) {
      int e = s * 16 + grp;
      if (e < dE0) { a0 += bf_lo(vA[s]); a1 += bf_hi(vA[s]); }
      if (e < dE1) { c0 += bf_lo(vB[s]); c1 += bf_hi(vB[s]); }
    }
#pragma unroll
    for (int m = 4; m <= 32; m <<= 1) {
      a0 += __shfl_xor(a0, m); a1 += __shfl_xor(a1, m);
      c0 += __shfl_xor(c0, m); c1 += __shfl_xor(c1, m);
    }
    if (grp == 0) {  // lanes 0..3 deposit dims [2ch, 2ch+1]
      float2 za = {a0, a1};
      float2 zc = {c0, c1};
      *(float2*)&zsA[w][ch * 2] = za;
      *(float2*)&zsB[w][ch * 2] = zc;
    }

    // ---- MLP node0 ----
    float tp = half ? 0.f : vb1;
    {
      const float4* zp = (const float4*)&zsA[w][half * 4];
      float4 z0 = zp[0];
      tp = fmaf(z0.x, wr1[0], tp); tp = fmaf(z0.y, wr1[1], tp);
      tp = fmaf(z0.z, wr1[2], tp); tp = fmaf(z0.w, wr1[3], tp);
    }
    tp += __shfl_xor(tp, 32);
    tp = fmaxf(tp, 0.f);
    if (!half) tsA[w][j] = tp;

    float op = half ? 0.f : vb2;
    {
      const float4* tpp = (const float4*)&tsA[w][half * 16];
      float4 t0 = tpp[0], t1 = tpp[1], t2 = tpp[2], t3 = tpp[3];
      op = fmaf(t0.x, wr2[0], op);  op = fmaf(t0.y, wr2[1], op);
      op = fmaf(t0.z, wr2[2], op);  op = fmaf(t0.w, wr2[3], op);
      op = fmaf(t1.x, wr2[4], op);  op = fmaf(t1.y, wr2[5], op);
      op = fmaf(t1.z, wr2[6], op);  op = fmaf(t1.w, wr2[7], op);
      op = fmaf(t2.x, wr2[8], op);  op = fmaf(t2.y, wr2[9], op);
      op = fmaf(t2.z, wr2[10], op); op = fmaf(t2.w, wr2[11], op);
      op = fmaf(t3.x, wr2[12], op); op = fmaf(t3.y, wr2[13], op);
      op = fmaf(t3.z, wr2[14], op); op = fmaf(t3.w, wr2[15], op);
    }
    op += __shfl_xor(op, 32);
    if (!half) {
      op = fmaxf(op, 0.f) * sc + sh;
      float hi = __shfl(op, j | 1);
      if ((j & 1) == 0) {
        unsigned pk = bf16_rne(op) | (bf16_rne(hi) << 16);
        ((unsigned*)hout16)[n0 * 16 + (j >> 1)] = pk;
      }
    }

    // ---- MLP node1 ----
    float tq = half ? 0.f : vb1;
    {
      const float4* zp = (const float4*)&zsB[w][half * 4];
      float4 z0 = zp[0];
      tq = fmaf(z0.x, wr1[0], tq); tq = fmaf(z0.y, wr1[1], tq);
      tq = fmaf(z0.z, wr1[2], tq); tq = fmaf(z0.w, wr1[3], tq);
    }
    tq += __shfl_xor(tq, 32);
    tq = fmaxf(tq, 0.f);
    if (!half) tsB[w][j] = tq;

    float oq = half ? 0.f : vb2;
    {
      const float4* tpp = (const float4*)&tsB[w][half * 16];
      float4 t0 = tpp[0], t1 = tpp[1], t2 = tpp[2], t3 = tpp[3];
      oq = fmaf(t0.x, wr2[0], oq);  oq = fmaf(t0.y, wr2[1], oq);
      oq = fmaf(t0.z, wr2[2], oq);  oq = fmaf(t0.w, wr2[3], oq);
      oq = fmaf(t1.x, wr2[4], oq);  oq = fmaf(t1.y, wr2[5], oq);
      oq = fmaf(t1.z, wr2[6], oq);  oq = fmaf(t1.w, wr2[7], oq);
      oq = fmaf(t2.x, wr2[8], oq);  oq = fmaf(t2.y, wr2[9], oq);
      oq = fmaf(t2.z, wr2[10], oq); oq = fmaf(t2.w, wr2[11], oq);
      oq = fmaf(t3.x, wr2[12], oq); oq = fmaf(t3.y, wr2[13], oq);
      oq = fmaf(t3.z, wr2[14], oq); oq = fmaf(t3.w, wr2[15], oq);
    }
    oq += __shfl_xor(oq, 32);
    if (!half) {
      oq = fmaxf(oq, 0.f) * sc + sh;
      float hi = __shfl(oq, j | 1);
      if ((j & 1) == 0) {
        unsigned pk = bf16_rne(oq) | (bf16_rne(hi) << 16);
        ((unsigned*)hout16)[n1 * 16 + (j >> 1)] = pk;
      }
    }
  }
}

// ---------------- conv2..5: TRANSPOSED gather, no reduction (R9) ----------------
// One 16-node group per wave. lane = (nl = lane&15 -> node, c = lane>>4 ->
// dims [8c..8c+7]). Per 4-slot batch: uint4 idx load from the node's csr row
// (pad slots = self id, always valid) + 4 uint4 row-gathers + guarded adds.
// Loop bound = per-group max degree (gmax). Accumulators ARE the final z:
// zero cross-lane reduction. MLP: z -> LDS, then proven per-node MLP x16.
__global__ __launch_bounds__(256) void gin_layer32(
    const unsigned short* __restrict__ hin16, const int* __restrict__ cnt,
    const int* __restrict__ csr, const int* __restrict__ gmax,
    const float* __restrict__ W1, const float* __restrict__ b1,
    const float* __restrict__ W2, const float* __restrict__ b2,
    const float* __restrict__ gamma, const float* __restrict__ beta,
    const float* __restrict__ mean, const float* __restrict__ var,
    unsigned short* __restrict__ hout16) {
  __shared__ __align__(16) float zs[4][16][36];   // 9.2 KB, stride 36
  __shared__ __align__(16) float ts[4][32];
  int tid = threadIdx.x;
  int w = __builtin_amdgcn_readfirstlane(tid >> 6);  // wave id, force-scalar
  int lane = tid & 63;
  int nl = lane & 15;    // node within group
  int c  = lane >> 4;    // 16-B chunk = dims [8c, 8c+7]
  int half = lane >> 5, j = lane & 31;  // MLP roles

  float wr1[16], wr2[16];
#pragma unroll
  for (int i = 0; i < 16; ++i) wr1[i] = W1[(half * 16 + i) * 32 + j];
#pragma unroll
  for (int i = 0; i < 16; ++i) wr2[i] = W2[(half * 16 + i) * 32 + j];
  float vb1 = b1[j], vb2 = b2[j];
  float sc = gamma[j] * rsqrtf(var[j] + BN_EPS);
  float sh = beta[j] - mean[j] * sc;

  const int NW = gridDim.x * 4;
  for (int g = blockIdx.x * 4 + w; g < NGRP; g += NW) {
    int node = g * 16 + nl;
    int dcnt = cnt[node];
    if (dcnt > 63) dcnt = 63;
    int dE = dcnt + 1;  // edges + self (self sits at slot dcnt via b2 init)
    int dmax = __builtin_amdgcn_readfirstlane(gmax[g]);
    int nb = (dmax + 3) >> 2;

    const int* crow = csr + (size_t)node * MAXDEG;
    float acc[8];
#pragma unroll
    for (int i = 0; i < 8; ++i) acc[i] = 0.f;

    uint4 i4 = *(const uint4*)crow;   // slots 0..3
    for (int b = 0; b < nb; ++b) {
      uint4 i4n = i4;
      if (b + 1 < nb) i4n = *(const uint4*)(crow + (b + 1) * 4);
      uint4 v0 = *(const uint4*)(hin16 + (size_t)i4.x * 32 + c * 8);
      uint4 v1 = *(const uint4*)(hin16 + (size_t)i4.y * 32 + c * 8);
      uint4 v2 = *(const uint4*)(hin16 + (size_t)i4.z * 32 + c * 8);
      uint4 v3 = *(const uint4*)(hin16 + (size_t)i4.w * 32 + c * 8);
      int s0 = b * 4;
      if (s0 + 0 < dE) {
        acc[0] += bf_lo(v0.x); acc[1] += bf_hi(v0.x);
        acc[2] += bf_lo(v0.y); acc[3] += bf_hi(v0.y);
        acc[4] += bf_lo(v0.z); acc[5] += bf_hi(v0.z);
        acc[6] += bf_lo(v0.w); acc[7] += bf_hi(v0.w);
      }
      if (s0 + 1 < dE) {
        acc[0] += bf_lo(v1.x); acc[1] += bf_hi(v1.x);
        acc[2] += bf_lo(v1.y); acc[3] += bf_hi(v1.y);
        acc[4] += bf_lo(v1.z); acc[5] += bf_hi(v1.z);
        acc[6] += bf_lo(v1.w); acc[7] += bf_hi(v1.w);
      }
      if (s0 + 2 < dE) {
        acc[0] += bf_lo(v2.x); acc[1] += bf_hi(v2.x);
        acc[2] += bf_lo(v2.y); acc[3] += bf_hi(v2.y);
        acc[4] += bf_lo(v2.z); acc[5] += bf_hi(v2.z);
        acc[6] += bf_lo(v2.w); acc[7] += bf_hi(v2.w);
      }
      if (s0 + 3 < dE) {
        acc[0] += bf_lo(v3.x); acc[1] += bf_hi(v3.x);
        acc[2] += bf_lo(v3.y); acc[3] += bf_hi(v3.y);
        acc[4] += bf_lo(v3.z); acc[5] += bf_hi(v3.z);
        acc[6] += bf_lo(v3.w); acc[7] += bf_hi(v3.w);
      }
      i4 = i4n;
    }

    // deposit z: lane (nl,c) owns dims [8c..8c+7] of node nl
    {
      float4 z0 = {acc[0], acc[1], acc[2], acc[3]};
      float4 z1 = {acc[4], acc[5], acc[6], acc[7]};
      *(float4*)&zs[w][nl][c * 8]     = z0;
      *(float4*)&zs[w][nl][c * 8 + 4] = z1;
    }

    // ---- per-node MLP x16 (proven structure) ----
    for (int p = 0; p < 16; ++p) {
      int np = g * 16 + p;
      float tp = half ? 0.f : vb1;
      {
        const float4* zp = (const float4*)&zs[w][p][half * 16];
        float4 q0 = zp[0], q1 = zp[1], q2 = zp[2], q3 = zp[3];
        tp = fmaf(q0.x, wr1[0], tp);  tp = fmaf(q0.y, wr1[1], tp);
        tp = fmaf(q0.z, wr1[2], tp);  tp = fmaf(q0.w, wr1[3], tp);
        tp = fmaf(q1.x, wr1[4], tp);  tp = fmaf(q1.y, wr1[5], tp);
        tp = fmaf(q1.z, wr1[6], tp);  tp = fmaf(q1.w, wr1[7], tp);
        tp = fmaf(q2.x, wr1[8], tp);  tp = fmaf(q2.y, wr1[9], tp);
        tp = fmaf(q2.z, wr1[10], tp); tp = fmaf(q2.w, wr1[11], tp);
        tp = fmaf(q3.x, wr1[12], tp); tp = fmaf(q3.y, wr1[13], tp);
        tp = fmaf(q3.z, wr1[14], tp); tp = fmaf(q3.w, wr1[15], tp);
      }
      tp += __shfl_xor(tp, 32);
      tp = fmaxf(tp, 0.f);
      if (!half) ts[w][j] = tp;

      float op = half ? 0.f : vb2;
      {
        const float4* tpp = (const float4*)&ts[w][half * 16];
        float4 q0 = tpp[0], q1 = tpp[1], q2 = tpp[2], q3 = tpp[3];
        op = fmaf(q0.x, wr2[0], op);  op = fmaf(q0.y, wr2[1], op);
        op = fmaf(q0.z, wr2[2], op);  op = fmaf(q0.w, wr2[3], op);
        op = fmaf(q1.x, wr2[4], op);  op = fmaf(q1.y, wr2[5], op);
        op = fmaf(q1.z, wr2[6], op);  op = fmaf(q1.w, wr2[7], op);
        op = fmaf(q2.x, wr2[8], op);  op = fmaf(q2.y, wr2[9], op);
        op = fmaf(q2.z, wr2[10], op); op = fmaf(q2.w, wr2[11], op);
        op = fmaf(q3.x, wr2[12], op); op = fmaf(q3.y, wr2[13], op);
        op = fmaf(q3.z, wr2[14], op); op = fmaf(q3.w, wr2[15], op);
      }
      op += __shfl_xor(op, 32);
      if (!half) {
        op = fmaxf(op, 0.f) * sc + sh;
        float hi = __shfl(op, j | 1);
        if ((j & 1) == 0) {
          unsigned pk = bf16_rne(op) | (bf16_rne(hi) << 16);
          ((unsigned*)hout16)[np * 16 + (j >> 1)] = pk;
        }
      }
    }
  }
}

// ---------------- pool: one block per graph (batch sorted), bf16 in ----------------
__global__ __launch_bounds__(256) void pool_kernel(const unsigned short* __restrict__ h16,
                                                   const int* __restrict__ batch,
                                                   float* __restrict__ g) {
  __shared__ int s_lo, s_hi;
  __shared__ float red[8][33];
  int gr = blockIdx.x;
  if (threadIdx.x == 0) {
    int lo = 0, hi = N_NODES;
    while (lo < hi) { int m = (lo + hi) >> 1; if (batch[m] < gr) lo = m + 1; else hi = m; }
    s_lo = lo;
  } else if (threadIdx.x == 1) {
    int lo = 0, hi = N_NODES;
    while (lo < hi) { int m = (lo + hi) >> 1; if (batch[m] < gr + 1) lo = m + 1; else hi = m; }
    s_hi = lo;
  }
  __syncthreads();
  int lo = s_lo, hi = s_hi;
  int j = threadIdx.x & 31;
  int nd = threadIdx.x >> 5;
  float acc = 0.f;
  for (int n = lo + nd; n < hi; n += 8)
    acc += __uint_as_float((unsigned)h16[n * 32 + j] << 16);
  red[nd][j] = acc;
  __syncthreads();
  if (threadIdx.x < 32) {
    float s = 0.f;
#pragma unroll
    for (int r = 0; r < 8; ++r) s += red[r][j];
    g[gr * 32 + j] = s;
  }
}

// ---------------- head (fp32) ----------------
__global__ __launch_bounds__(256) void head_kernel(
    const float* __restrict__ g, const float* __restrict__ W1, const float* __restrict__ b1,
    const float* __restrict__ W2, const float* __restrict__ b2, float* __restrict__ out) {
  __shared__ float sW1[1024], sb1[32];
  __shared__ float sW2[64], sb2[2];
  __shared__ float zb[8][33], tb[8][33], lb[8][2];
  int tid = threadIdx.x;
  for (int i = tid; i < 1024; i += 256) sW1[i] = W1[i];
  if (tid < 64) sW2[tid] = W2[tid];
  if (tid < 32) sb1[tid] = b1[tid];
  if (tid < 2) sb2[tid] = b2[tid];
  int nd = tid >> 5;
  int gr = blockIdx.x * 8 + nd;
  int j = tid & 31;
  __syncthreads();
  float z = (gr < N_GRAPHS) ? g[gr * 32 + j] : 0.f;
  zb[nd][j] = z;
  __syncthreads();
  float t = sb1[j];
#pragma unroll
  for (int k = 0; k < 32; ++k) t = fmaf(zb[nd][k], sW1[k * 32 + j], t);
  t = fmaxf(t, 0.f);
  tb[nd][j] = t;
  __syncthreads();
  if (j < 2) {
    float l = sb2[j];
#pragma unroll
    for (int k = 0; k < 32; ++k) l = fmaf(tb[nd][k], sW2[k * 2 + j], l);
    lb[nd][j] = l;
  }
  __syncthreads();
  if (gr < N_GRAPHS && j < 2) {
    float l0 = lb[nd][0], l1 = lb[nd][1];
    float m = fmaxf(l0, l1);
    float lse = m + logf(expf(l0 - m) + expf(l1 - m));
    out[gr * 2 + j] = lb[nd][j] - lse;
  }
}

extern "C" void kernel_launch(void* const* d_in, const int* in_sizes, int n_in,
                              void* d_out, int out_size, void* d_ws, size_t ws_size,
                              hipStream_t stream) {
  const float* x     = (const float*)d_in[0];
  const int*   eidx  = (const int*)d_in[1];
  const int*   batch = (const int*)d_in[2];
  const float* c1W1  = (const float*)d_in[3];
  const float* c1b1  = (const float*)d_in[4];
  const float* c1W2  = (const float*)d_in[5];
  const float* c1b2  = (const float*)d_in[6];
  const float* csW1  = (const float*)d_in[7];
  const float* csb1  = (const float*)d_in[8];
  const float* csW2  = (const float*)d_in[9];
  const float* csb2  = (const float*)d_in[10];
  const float* bng   = (const float*)d_in[11];
  const float* bnb   = (const float*)d_in[12];
  const float* bnm   = (const float*)d_in[13];
  const float* bnv   = (const float*)d_in[14];
  const float* fc1W  = (const float*)d_in[15];
  const float* fc1b  = (const float*)d_in[16];
  const float* fc2W  = (const float*)d_in[17];
  const float* fc2b  = (const float*)d_in[18];
  float* out = (float*)d_out;

  const int* src = eidx;
  const int* dst = eidx + N_EDGES;

  // workspace (~50.3 MB)
  char* p = (char*)d_ws;
  unsigned short* hA16 = (unsigned short*)p; p += (size_t)N_NODES * 32 * 2;   // 6.4 MB
  unsigned short* hB16 = (unsigned short*)p; p += (size_t)N_NODES * 32 * 2;   // 6.4 MB
  int*      cnt  = (int*)p;      p += (size_t)N_NODES * 4;                    // 0.4 MB
  int*      csr  = (int*)p;      p += (size_t)NBKT * 128 * MAXDEG * 4;        // 25.6 MB
  unsigned* ebuf = (unsigned*)p; p += (size_t)NBKT * BCAP * 4;                // 11.2 MB
  int*      gCur = (int*)p;      p += 1024 * 4;
  int*      gmax = (int*)p;      p += (size_t)(NBKT * 8) * 4;                 // 25 KB
  float*    g    = (float*)p;    p += (size_t)N_GRAPHS * 32 * 4;
  // xc (bf16 [N,8], 1.6 MB) aliases ebuf: ebuf is dead after b2_csr completes
  unsigned* xc = ebuf;

  // ---- build: bucket pass + per-bucket padded-CSR pass ----
  (void)hipMemsetAsync(gCur, 0, 1024 * 4, stream);
  b1_bucket<<<(N_EDGES + E_PER_BLK - 1) / E_PER_BLK, 1024, 0, stream>>>(src, dst, gCur, ebuf);
  b2_csr<<<NBKT, 512, 0, stream>>>(ebuf, gCur, cnt, csr, gmax);

  // ---- x -> bf16 padded rows (after b2: xc aliases ebuf) ----
  xcvt_kernel<<<(N_NODES * 4 + 255) / 256, 256, 0, stream>>>(x, xc);

  // ---- conv1 (7->32) + relu + bn0 ----
  gin1<<<2048, 256, 0, stream>>>(
      (const unsigned short*)xc, cnt, csr, c1W1, c1b1, c1W2, c1b2,
      bng, bnb, bnm, bnv, hA16);

  // ---- conv2..5 (32->32) + relu + bn1..4, transposed gather ----
  unsigned short* cur = hA16;
  unsigned short* nxt = hB16;
  for (int i = 0; i < 4; ++i) {
    gin_layer32<<<(NGRP + 3) / 4, 256, 0, stream>>>(
        cur, cnt, csr, gmax,
        csW1 + (size_t)i * 1024, csb1 + (size_t)i * 32,
        csW2 + (size_t)i * 1024, csb2 + (size_t)i * 32,
        bng + (size_t)(i + 1) * 32, bnb + (size_t)(i + 1) * 32,
        bnm + (size_t)(i + 1) * 32, bnv + (size_t)(i + 1) * 32, nxt);
    unsigned short* tmp = cur; cur = nxt; nxt = tmp;
  }

  pool_kernel<<<N_GRAPHS, 256, 0, stream>>>(cur, batch, g);
  head_kernel<<<(N_GRAPHS + 7) / 8, 256, 0, stream>>>(g, fc1W, fc1b, fc2W, fc2b, out);
}

// Round 11
// 341.877 us; speedup vs baseline: 1.1181x; 1.0031x over previous
//
#include <hip/hip_runtime.h>

#define N_NODES  100000
#define N_EDGES  2000000
#define N_GRAPHS 1000
#define NFEAT    7
#define BN_EPS   1e-5f
#define MAXDEG   64    // in-degree ~ Poisson(20); P(max over 100k > 63) < 1e-9

#define BSH      7     // 128-node dst buckets
#define NBKT     782   // ceil(100000/128)
#define BCAP     3584  // per-bucket edge cap: mean 2560 + 20 sigma
#define E_PER_BLK 4096
#define NGRP     6250  // 100000/16 node groups

// bf16 helpers (storage only; all arithmetic fp32)
__device__ __forceinline__ unsigned bf16_rne(float f) {
  unsigned u = __float_as_uint(f);
  return (u + 0x7FFFu + ((u >> 16) & 1u)) >> 16;
}
__device__ __forceinline__ float bf_lo(unsigned u) { return __uint_as_float(u << 16); }
__device__ __forceinline__ float bf_hi(unsigned u) { return __uint_as_float(u & 0xFFFF0000u); }

// ---------------- b1: bucket edges by dst>>7, block-contiguous writes ----------------
__global__ __launch_bounds__(1024) void b1_bucket(const int* __restrict__ src,
                                                  const int* __restrict__ dst,
                                                  int* __restrict__ gCur,
                                                  unsigned* __restrict__ ebuf) {
  __shared__ int hist[NBKT], base[NBKT];
  int tid = threadIdx.x;
  for (int i = tid; i < NBKT; i += 1024) hist[i] = 0;
  __syncthreads();
  unsigned pk[4];
  int bo[4];
  int e0 = blockIdx.x * E_PER_BLK;
#pragma unroll
  for (int k = 0; k < 4; ++k) {
    int e = e0 + k * 1024 + tid;
    if (e < N_EDGES) {
      int d = dst[e], s = src[e];
      int b = d >> BSH;
      int off = atomicAdd(&hist[b], 1);
      pk[k] = ((unsigned)(d & 127) << 17) | (unsigned)s;
      bo[k] = (b << 17) | off;
    } else {
      bo[k] = -1;
    }
  }
  __syncthreads();
  for (int i = tid; i < NBKT; i += 1024)
    base[i] = hist[i] ? atomicAdd(&gCur[i], hist[i]) : 0;
  __syncthreads();
#pragma unroll
  for (int k = 0; k < 4; ++k) {
    if (bo[k] >= 0) {
      int b = bo[k] >> 17, off = bo[k] & 0x1FFFF;
      int p = base[b] + off;
      if (p < BCAP) ebuf[(size_t)b * BCAP + p] = pk[k];
    }
  }
}

// ---------------- b2: one block per bucket -> padded csr (pad=self) + cnt + gmax ----------------
__global__ __launch_bounds__(512) void b2_csr(const unsigned* __restrict__ ebuf,
                                              const int* __restrict__ gCnt,
                                              int* __restrict__ cnt,
                                              int* __restrict__ csr,
                                              int* __restrict__ gmax) {
  __shared__ int hist[128];
  __shared__ int stage[128 * MAXDEG];
  int b = blockIdx.x, tid = threadIdx.x;
  if (tid < 128) hist[tid] = 0;
  // init stage to self-node id: pad slots become valid self rows, and slot
  // cnt (first un-filled) supplies the GIN self term.
  for (int i = tid; i < 128 * MAXDEG; i += 512) stage[i] = (b << BSH) + (i >> 6);
  __syncthreads();
  int n = gCnt[b];
  if (n > BCAP) n = BCAP;
  const unsigned* eb = ebuf + (size_t)b * BCAP;
  for (int i = tid; i < n; i += 512) {
    unsigned pk = eb[i];
    int dloc = (int)(pk >> 17);
    int slot = atomicAdd(&hist[dloc], 1);
    if (slot < MAXDEG) stage[(dloc << 6) + slot] = (int)(pk & 0x1FFFFu);
  }
  __syncthreads();
  if (tid < 128) {
    int gnode = (b << BSH) + tid;
    if (gnode < N_NODES) cnt[gnode] = hist[tid];
  }
  if (tid < 8) {  // per-16-node-group max effective degree (dE = min(d,63)+1)
    int mx = 1;
#pragma unroll
    for (int k = 0; k < 16; ++k) {
      int d = hist[tid * 16 + k];
      if (d > 63) d = 63;
      if (d + 1 > mx) mx = d + 1;
    }
    gmax[(b << 3) + tid] = mx;
  }
  const int4* st4 = (const int4*)stage;
  int4* dst4 = (int4*)(csr + (size_t)b * (128 * MAXDEG));
  for (int i = tid; i < 128 * MAXDEG / 4; i += 512) dst4[i] = st4[i];
}

// ---------------- xcvt: x (fp32 [N,7]) -> xc (bf16 [N,8], pad dim7 = 0) ----------------
__global__ __launch_bounds__(256) void xcvt_kernel(const float* __restrict__ x,
                                                   unsigned* __restrict__ xc) {
  int i = blockIdx.x * 256 + threadIdx.x;
  if (i >= N_NODES * 4) return;
  int n = i >> 2, p = i & 3;
  float lo = x[n * 7 + 2 * p];
  float hi = (2 * p + 1 < 7) ? x[n * 7 + 2 * p + 1] : 0.f;
  xc[i] = bf16_rne(lo) | (bf16_rne(hi) << 16);
}

// ---------------- conv1 (7->32): TRANSPOSED gather (R10, ported from R9) ----------------
// 16-node group per wave. lane = (nl = lane&15 -> node, c = lane>>4 ->
// dims [2c, 2c+1], 4B chunk). Per 4-slot batch: uint4 idx load (pad=self,
// always valid) + 4 x 4B gathers (xc table = 1.6 MB, L2-resident) + guarded
// adds. No cross-lane reduction. MLP: z -> LDS, proven per-node MLP x16.
__global__ __launch_bounds__(256) void gin1(
    const unsigned short* __restrict__ xc16, const int* __restrict__ cnt,
    const int* __restrict__ csr, const int* __restrict__ gmax,
    const float* __restrict__ W1, const float* __restrict__ b1,
    const float* __restrict__ W2, const float* __restrict__ b2,
    const float* __restrict__ gamma, const float* __restrict__ beta,
    const float* __restrict__ mean, const float* __restrict__ var,
    unsigned short* __restrict__ hout16) {
  __shared__ __align__(16) float zs[4][16][12];   // stride 12: 2-way max on writes
  __shared__ __align__(16) float ts[4][32];
  int tid = threadIdx.x;
  int w = __builtin_amdgcn_readfirstlane(tid >> 6);
  int lane = tid & 63;
  int nl = lane & 15;    // node within group
  int c  = lane >> 4;    // 4-B chunk = dims [2c, 2c+1]
  int half = lane >> 5, j = lane & 31;  // MLP roles

  float wr1[4], wr2[16];
#pragma unroll
  for (int i = 0; i < 4; ++i) {
    int k = half * 4 + i;
    wr1[i] = (k < 7) ? W1[k * 32 + j] : 0.f;
  }
#pragma unroll
  for (int i = 0; i < 16; ++i) wr2[i] = W2[(half * 16 + i) * 32 + j];
  float vb1 = b1[j], vb2 = b2[j];
  float sc = gamma[j] * rsqrtf(var[j] + BN_EPS);
  float sh = beta[j] - mean[j] * sc;

  const unsigned* xc32 = (const unsigned*)xc16;  // 4 x unsigned per 16-B row

  const int NW = gridDim.x * 4;
  for (int g = blockIdx.x * 4 + w; g < NGRP; g += NW) {
    int node = g * 16 + nl;
    int dcnt = cnt[node];
    if (dcnt > 63) dcnt = 63;
    int dE = dcnt + 1;  // edges + self (slot dcnt = self via b2 init)
    int dmax = __builtin_amdgcn_readfirstlane(gmax[g]);
    int nb = (dmax + 3) >> 2;

    const int* crow = csr + (size_t)node * MAXDEG;
    float a0 = 0.f, a1 = 0.f;

    uint4 i4 = *(const uint4*)crow;   // slots 0..3
    for (int b = 0; b < nb; ++b) {
      uint4 i4n = i4;
      if (b + 1 < nb) i4n = *(const uint4*)(crow + (b + 1) * 4);
      unsigned v0 = xc32[(size_t)i4.x * 4 + c];
      unsigned v1 = xc32[(size_t)i4.y * 4 + c];
      unsigned v2 = xc32[(size_t)i4.z * 4 + c];
      unsigned v3 = xc32[(size_t)i4.w * 4 + c];
      int s0 = b * 4;
      if (s0 + 0 < dE) { a0 += bf_lo(v0); a1 += bf_hi(v0); }
      if (s0 + 1 < dE) { a0 += bf_lo(v1); a1 += bf_hi(v1); }
      if (s0 + 2 < dE) { a0 += bf_lo(v2); a1 += bf_hi(v2); }
      if (s0 + 3 < dE) { a0 += bf_lo(v3); a1 += bf_hi(v3); }
      i4 = i4n;
    }

    // deposit z: lane (nl,c) owns dims [2c, 2c+1] of node nl
    {
      float2 z0 = {a0, a1};
      *(float2*)&zs[w][nl][c * 2] = z0;
    }

    // ---- per-node MLP x16 (proven gin1 MLP, z from zs) ----
    for (int p = 0; p < 16; ++p) {
      int np = g * 16 + p;
      float tp = half ? 0.f : vb1;
      {
        const float4* zp = (const float4*)&zs[w][p][half * 4];
        float4 z0 = zp[0];
        tp = fmaf(z0.x, wr1[0], tp); tp = fmaf(z0.y, wr1[1], tp);
        tp = fmaf(z0.z, wr1[2], tp); tp = fmaf(z0.w, wr1[3], tp);
      }
      tp += __shfl_xor(tp, 32);
      tp = fmaxf(tp, 0.f);
      if (!half) ts[w][j] = tp;

      float op = half ? 0.f : vb2;
      {
        const float4* tpp = (const float4*)&ts[w][half * 16];
        float4 t0 = tpp[0], t1 = tpp[1], t2 = tpp[2], t3 = tpp[3];
        op = fmaf(t0.x, wr2[0], op);  op = fmaf(t0.y, wr2[1], op);
        op = fmaf(t0.z, wr2[2], op);  op = fmaf(t0.w, wr2[3], op);
        op = fmaf(t1.x, wr2[4], op);  op = fmaf(t1.y, wr2[5], op);
        op = fmaf(t1.z, wr2[6], op);  op = fmaf(t1.w, wr2[7], op);
        op = fmaf(t2.x, wr2[8], op);  op = fmaf(t2.y, wr2[9], op);
        op = fmaf(t2.z, wr2[10], op); op = fmaf(t2.w, wr2[11], op);
        op = fmaf(t3.x, wr2[12], op); op = fmaf(t3.y, wr2[13], op);
        op = fmaf(t3.z, wr2[14], op); op = fmaf(t3.w, wr2[15], op);
      }
      op += __shfl_xor(op, 32);
      if (!half) {
        op = fmaxf(op, 0.f) * sc + sh;
        float hi = __shfl(op, j | 1);
        if ((j & 1) == 0) {
          unsigned pk = bf16_rne(op) | (bf16_rne(hi) << 16);
          ((unsigned*)hout16)[np * 16 + (j >> 1)] = pk;
        }
      }
    }
  }
}

// ---------------- conv2..5: TRANSPOSED gather, no reduction (proven R9) ----------------
__global__ __launch_bounds__(256) void gin_layer32(
    const unsigned short* __restrict__ hin16, const int* __restrict__ cnt,
    const int* __restrict__ csr, const int* __restrict__ gmax,
    const float* __restrict__ W1, const float* __restrict__ b1,
    const float* __restrict__ W2, const float* __restrict__ b2,
    const float* __restrict__ gamma, const float* __restrict__ beta,
    const float* __restrict__ mean, const float* __restrict__ var,
    unsigned short* __restrict__ hout16) {
  __shared__ __align__(16) float zs[4][16][36];   // 9.2 KB, stride 36
  __shared__ __align__(16) float ts[4][32];
  int tid = threadIdx.x;
  int w = __builtin_amdgcn_readfirstlane(tid >> 6);  // wave id, force-scalar
  int lane = tid & 63;
  int nl = lane & 15;    // node within group
  int c  = lane >> 4;    // 16-B chunk = dims [8c, 8c+7]
  int half = lane >> 5, j = lane & 31;  // MLP roles

  float wr1[16], wr2[16];
#pragma unroll
  for (int i = 0; i < 16; ++i) wr1[i] = W1[(half * 16 + i) * 32 + j];
#pragma unroll
  for (int i = 0; i < 16; ++i) wr2[i] = W2[(half * 16 + i) * 32 + j];
  float vb1 = b1[j], vb2 = b2[j];
  float sc = gamma[j] * rsqrtf(var[j] + BN_EPS);
  float sh = beta[j] - mean[j] * sc;

  const int NW = gridDim.x * 4;
  for (int g = blockIdx.x * 4 + w; g < NGRP; g += NW) {
    int node = g * 16 + nl;
    int dcnt = cnt[node];
    if (dcnt > 63) dcnt = 63;
    int dE = dcnt + 1;  // edges + self (self sits at slot dcnt via b2 init)
    int dmax = __builtin_amdgcn_readfirstlane(gmax[g]);
    int nb = (dmax + 3) >> 2;

    const int* crow = csr + (size_t)node * MAXDEG;
    float acc[8];
#pragma unroll
    for (int i = 0; i < 8; ++i) acc[i] = 0.f;

    uint4 i4 = *(const uint4*)crow;   // slots 0..3
    for (int b = 0; b < nb; ++b) {
      uint4 i4n = i4;
      if (b + 1 < nb) i4n = *(const uint4*)(crow + (b + 1) * 4);
      uint4 v0 = *(const uint4*)(hin16 + (size_t)i4.x * 32 + c * 8);
      uint4 v1 = *(const uint4*)(hin16 + (size_t)i4.y * 32 + c * 8);
      uint4 v2 = *(const uint4*)(hin16 + (size_t)i4.z * 32 + c * 8);
      uint4 v3 = *(const uint4*)(hin16 + (size_t)i4.w * 32 + c * 8);
      int s0 = b * 4;
      if (s0 + 0 < dE) {
        acc[0] += bf_lo(v0.x); acc[1] += bf_hi(v0.x);
        acc[2] += bf_lo(v0.y); acc[3] += bf_hi(v0.y);
        acc[4] += bf_lo(v0.z); acc[5] += bf_hi(v0.z);
        acc[6] += bf_lo(v0.w); acc[7] += bf_hi(v0.w);
      }
      if (s0 + 1 < dE) {
        acc[0] += bf_lo(v1.x); acc[1] += bf_hi(v1.x);
        acc[2] += bf_lo(v1.y); acc[3] += bf_hi(v1.y);
        acc[4] += bf_lo(v1.z); acc[5] += bf_hi(v1.z);
        acc[6] += bf_lo(v1.w); acc[7] += bf_hi(v1.w);
      }
      if (s0 + 2 < dE) {
        acc[0] += bf_lo(v2.x); acc[1] += bf_hi(v2.x);
        acc[2] += bf_lo(v2.y); acc[3] += bf_hi(v2.y);
        acc[4] += bf_lo(v2.z); acc[5] += bf_hi(v2.z);
        acc[6] += bf_lo(v2.w); acc[7] += bf_hi(v2.w);
      }
      if (s0 + 3 < dE) {
        acc[0] += bf_lo(v3.x); acc[1] += bf_hi(v3.x);
        acc[2] += bf_lo(v3.y); acc[3] += bf_hi(v3.y);
        acc[4] += bf_lo(v3.z); acc[5] += bf_hi(v3.z);
        acc[6] += bf_lo(v3.w); acc[7] += bf_hi(v3.w);
      }
      i4 = i4n;
    }

    // deposit z: lane (nl,c) owns dims [8c..8c+7] of node nl
    {
      float4 z0 = {acc[0], acc[1], acc[2], acc[3]};
      float4 z1 = {acc[4], acc[5], acc[6], acc[7]};
      *(float4*)&zs[w][nl][c * 8]     = z0;
      *(float4*)&zs[w][nl][c * 8 + 4] = z1;
    }

    // ---- per-node MLP x16 (proven structure) ----
    for (int p = 0; p < 16; ++p) {
      int np = g * 16 + p;
      float tp = half ? 0.f : vb1;
      {
        const float4* zp = (const float4*)&zs[w][p][half * 16];
        float4 q0 = zp[0], q1 = zp[1], q2 = zp[2], q3 = zp[3];
        tp = fmaf(q0.x, wr1[0], tp);  tp = fmaf(q0.y, wr1[1], tp);
        tp = fmaf(q0.z, wr1[2], tp);  tp = fmaf(q0.w, wr1[3], tp);
        tp = fmaf(q1.x, wr1[4], tp);  tp = fmaf(q1.y, wr1[5], tp);
        tp = fmaf(q1.z, wr1[6], tp);  tp = fmaf(q1.w, wr1[7], tp);
        tp = fmaf(q2.x, wr1[8], tp);  tp = fmaf(q2.y, wr1[9], tp);
        tp = fmaf(q2.z, wr1[10], tp); tp = fmaf(q2.w, wr1[11], tp);
        tp = fmaf(q3.x, wr1[12], tp); tp = fmaf(q3.y, wr1[13], tp);
        tp = fmaf(q3.z, wr1[14], tp); tp = fmaf(q3.w, wr1[15], tp);
      }
      tp += __shfl_xor(tp, 32);
      tp = fmaxf(tp, 0.f);
      if (!half) ts[w][j] = tp;

      float op = half ? 0.f : vb2;
      {
        const float4* tpp = (const float4*)&ts[w][half * 16];
        float4 q0 = tpp[0], q1 = tpp[1], q2 = tpp[2], q3 = tpp[3];
        op = fmaf(q0.x, wr2[0], op);  op = fmaf(q0.y, wr2[1], op);
        op = fmaf(q0.z, wr2[2], op);  op = fmaf(q0.w, wr2[3], op);
        op = fmaf(q1.x, wr2[4], op);  op = fmaf(q1.y, wr2[5], op);
        op = fmaf(q1.z, wr2[6], op);  op = fmaf(q1.w, wr2[7], op);
        op = fmaf(q2.x, wr2[8], op);  op = fmaf(q2.y, wr2[9], op);
        op = fmaf(q2.z, wr2[10], op); op = fmaf(q2.w, wr2[11], op);
        op = fmaf(q3.x, wr2[12], op); op = fmaf(q3.y, wr2[13], op);
        op = fmaf(q3.z, wr2[14], op); op = fmaf(q3.w, wr2[15], op);
      }
      op += __shfl_xor(op, 32);
      if (!half) {
        op = fmaxf(op, 0.f) * sc + sh;
        float hi = __shfl(op, j | 1);
        if ((j & 1) == 0) {
          unsigned pk = bf16_rne(op) | (bf16_rne(hi) << 16);
          ((unsigned*)hout16)[np * 16 + (j >> 1)] = pk;
        }
      }
    }
  }
}

// ---------------- pool: one block per graph (batch sorted), bf16 in ----------------
__global__ __launch_bounds__(256) void pool_kernel(const unsigned short* __restrict__ h16,
                                                   const int* __restrict__ batch,
                                                   float* __restrict__ g) {
  __shared__ int s_lo, s_hi;
  __shared__ float red[8][33];
  int gr = blockIdx.x;
  if (threadIdx.x == 0) {
    int lo = 0, hi = N_NODES;
    while (lo < hi) { int m = (lo + hi) >> 1; if (batch[m] < gr) lo = m + 1; else hi = m; }
    s_lo = lo;
  } else if (threadIdx.x == 1) {
    int lo = 0, hi = N_NODES;
    while (lo < hi) { int m = (lo + hi) >> 1; if (batch[m] < gr + 1) lo = m + 1; else hi = m; }
    s_hi = lo;
  }
  __syncthreads();
  int lo = s_lo, hi = s_hi;
  int j = threadIdx.x & 31;
  int nd = threadIdx.x >> 5;
  float acc = 0.f;
  for (int n = lo + nd; n < hi; n += 8)
    acc += __uint_as_float((unsigned)h16[n * 32 + j] << 16);
  red[nd][j] = acc;
  __syncthreads();
  if (threadIdx.x < 32) {
    float s = 0.f;
#pragma unroll
    for (int r = 0; r < 8; ++r) s += red[r][j];
    g[gr * 32 + j] = s;
  }
}

// ---------------- head (fp32) ----------------
__global__ __launch_bounds__(256) void head_kernel(
    const float* __restrict__ g, const float* __restrict__ W1, const float* __restrict__ b1,
    const float* __restrict__ W2, const float* __restrict__ b2, float* __restrict__ out) {
  __shared__ float sW1[1024], sb1[32];
  __shared__ float sW2[64], sb2[2];
  __shared__ float zb[8][33], tb[8][33], lb[8][2];
  int tid = threadIdx.x;
  for (int i = tid; i < 1024; i += 256) sW1[i] = W1[i];
  if (tid < 64) sW2[tid] = W2[tid];
  if (tid < 32) sb1[tid] = b1[tid];
  if (tid < 2) sb2[tid] = b2[tid];
  int nd = tid >> 5;
  int gr = blockIdx.x * 8 + nd;
  int j = tid & 31;
  __syncthreads();
  float z = (gr < N_GRAPHS) ? g[gr * 32 + j] : 0.f;
  zb[nd][j] = z;
  __syncthreads();
  float t = sb1[j];
#pragma unroll
  for (int k = 0; k < 32; ++k) t = fmaf(zb[nd][k], sW1[k * 32 + j], t);
  t = fmaxf(t, 0.f);
  tb[nd][j] = t;
  __syncthreads();
  if (j < 2) {
    float l = sb2[j];
#pragma unroll
    for (int k = 0; k < 32; ++k) l = fmaf(tb[nd][k], sW2[k * 2 + j], l);
    lb[nd][j] = l;
  }
  __syncthreads();
  if (gr < N_GRAPHS && j < 2) {
    float l0 = lb[nd][0], l1 = lb[nd][1];
    float m = fmaxf(l0, l1);
    float lse = m + logf(expf(l0 - m) + expf(l1 - m));
    out[gr * 2 + j] = lb[nd][j] - lse;
  }
}

extern "C" void kernel_launch(void* const* d_in, const int* in_sizes, int n_in,
                              void* d_out, int out_size, void* d_ws, size_t ws_size,
                              hipStream_t stream) {
  const float* x     = (const float*)d_in[0];
  const int*   eidx  = (const int*)d_in[1];
  const int*   batch = (const int*)d_in[2];
  const float* c1W1  = (const float*)d_in[3];
  const float* c1b1  = (const float*)d_in[4];
  const float* c1W2  = (const float*)d_in[5];
  const float* c1b2  = (const float*)d_in[6];
  const float* csW1  = (const float*)d_in[7];
  const float* csb1  = (const float*)d_in[8];
  const float* csW2  = (const float*)d_in[9];
  const float* csb2  = (const float*)d_in[10];
  const float* bng   = (const float*)d_in[11];
  const float* bnb   = (const float*)d_in[12];
  const float* bnm   = (const float*)d_in[13];
  const float* bnv   = (const float*)d_in[14];
  const float* fc1W  = (const float*)d_in[15];
  const float* fc1b  = (const float*)d_in[16];
  const float* fc2W  = (const float*)d_in[17];
  const float* fc2b  = (const float*)d_in[18];
  float* out = (float*)d_out;

  const int* src = eidx;
  const int* dst = eidx + N_EDGES;

  // workspace (~50.3 MB)
  char* p = (char*)d_ws;
  unsigned short* hA16 = (unsigned short*)p; p += (size_t)N_NODES * 32 * 2;   // 6.4 MB
  unsigned short* hB16 = (unsigned short*)p; p += (size_t)N_NODES * 32 * 2;   // 6.4 MB
  int*      cnt  = (int*)p;      p += (size_t)N_NODES * 4;                    // 0.4 MB
  int*      csr  = (int*)p;      p += (size_t)NBKT * 128 * MAXDEG * 4;        // 25.6 MB
  unsigned* ebuf = (unsigned*)p; p += (size_t)NBKT * BCAP * 4;                // 11.2 MB
  int*      gCur = (int*)p;      p += 1024 * 4;
  int*      gmax = (int*)p;      p += (size_t)(NBKT * 8) * 4;                 // 25 KB
  float*    g    = (float*)p;    p += (size_t)N_GRAPHS * 32 * 4;
  // xc (bf16 [N,8], 1.6 MB) aliases ebuf: ebuf is dead after b2_csr completes
  unsigned* xc = ebuf;

  // ---- build: bucket pass + per-bucket padded-CSR pass ----
  (void)hipMemsetAsync(gCur, 0, 1024 * 4, stream);
  b1_bucket<<<(N_EDGES + E_PER_BLK - 1) / E_PER_BLK, 1024, 0, stream>>>(src, dst, gCur, ebuf);
  b2_csr<<<NBKT, 512, 0, stream>>>(ebuf, gCur, cnt, csr, gmax);

  // ---- x -> bf16 padded rows (after b2: xc aliases ebuf) ----
  xcvt_kernel<<<(N_NODES * 4 + 255) / 256, 256, 0, stream>>>(x, xc);

  // ---- conv1 (7->32) + relu + bn0, transposed gather ----
  gin1<<<(NGRP + 3) / 4, 256, 0, stream>>>(
      (const unsigned short*)xc, cnt, csr, gmax, c1W1, c1b1, c1W2, c1b2,
      bng, bnb, bnm, bnv, hA16);

  // ---- conv2..5 (32->32) + relu + bn1..4, transposed gather ----
  unsigned short* cur = hA16;
  unsigned short* nxt = hB16;
  for (int i = 0; i < 4; ++i) {
    gin_layer32<<<(NGRP + 3) / 4, 256, 0, stream>>>(
        cur, cnt, csr, gmax,
        csW1 + (size_t)i * 1024, csb1 + (size_t)i * 32,
        csW2 + (size_t)i * 1024, csb2 + (size_t)i * 32,
        bng + (size_t)(i + 1) * 32, bnb + (size_t)(i + 1) * 32,
        bnm + (size_t)(i + 1) * 32, bnv + (size_t)(i + 1) * 32, nxt);
    unsigned short* tmp = cur; cur = nxt; nxt = tmp;
  }

  pool_kernel<<<N_GRAPHS, 256, 0, stream>>>(cur, batch, g);
  head_kernel<<<(N_GRAPHS + 7) / 8, 256, 0, stream>>>(g, fc1W, fc1b, fc2W, fc2b, out);
}

// Round 14
// 313.176 us; speedup vs baseline: 1.2206x; 1.0916x over previous
//
#include <hip/hip_runtime.h>

#define N_NODES  100000
#define N_EDGES  2000000
#define N_GRAPHS 1000
#define NFEAT    7
#define BN_EPS   1e-5f
#define MAXDEG   64    // in-degree ~ Poisson(20); P(max over 100k > 63) < 1e-9

#define BSH      7     // 128-node dst buckets
#define NBKT     782   // ceil(100000/128)
#define BCAP     3584  // per-bucket edge cap: mean 2560 + 20 sigma
#define E_PER_BLK 4096
#define NGRP     6250  // 100000/16 node groups

// bf16 helpers (storage only; arithmetic fp32 unless noted)
__device__ __forceinline__ unsigned bf16_rne(float f) {
  unsigned u = __float_as_uint(f);
  return (u + 0x7FFFu + ((u >> 16) & 1u)) >> 16;
}
__device__ __forceinline__ float bf_lo(unsigned u) { return __uint_as_float(u << 16); }
__device__ __forceinline__ float bf_hi(unsigned u) { return __uint_as_float(u & 0xFFFF0000u); }

// MFMA fragment types (gfx950)
typedef __bf16 bf16x8 __attribute__((ext_vector_type(8)));
typedef float  f32x4  __attribute__((ext_vector_type(4)));

// ---------------- b1: bucket edges by dst>>7, block-contiguous writes ----------------
__global__ __launch_bounds__(1024) void b1_bucket(const int* __restrict__ src,
                                                  const int* __restrict__ dst,
                                                  int* __restrict__ gCur,
                                                  unsigned* __restrict__ ebuf) {
  __shared__ int hist[NBKT], base[NBKT];
  int tid = threadIdx.x;
  for (int i = tid; i < NBKT; i += 1024) hist[i] = 0;
  __syncthreads();
  unsigned pk[4];
  int bo[4];
  int e0 = blockIdx.x * E_PER_BLK;
#pragma unroll
  for (int k = 0; k < 4; ++k) {
    int e = e0 + k * 1024 + tid;
    if (e < N_EDGES) {
      int d = dst[e], s = src[e];
      int b = d >> BSH;
      int off = atomicAdd(&hist[b], 1);
      pk[k] = ((unsigned)(d & 127) << 17) | (unsigned)s;
      bo[k] = (b << 17) | off;
    } else {
      bo[k] = -1;
    }
  }
  __syncthreads();
  for (int i = tid; i < NBKT; i += 1024)
    base[i] = hist[i] ? atomicAdd(&gCur[i], hist[i]) : 0;
  __syncthreads();
#pragma unroll
  for (int k = 0; k < 4; ++k) {
    if (bo[k] >= 0) {
      int b = bo[k] >> 17, off = bo[k] & 0x1FFFF;
      int p = base[b] + off;
      if (p < BCAP) ebuf[(size_t)b * BCAP + p] = pk[k];
    }
  }
}

// ---------------- b2: one block per bucket -> padded csr (pad=self) + cnt + gmax ----------------
__global__ __launch_bounds__(512) void b2_csr(const unsigned* __restrict__ ebuf,
                                              const int* __restrict__ gCnt,
                                              int* __restrict__ cnt,
                                              int* __restrict__ csr,
                                              int* __restrict__ gmax) {
  __shared__ int hist[128];
  __shared__ int stage[128 * MAXDEG];
  int b = blockIdx.x, tid = threadIdx.x;
  if (tid < 128) hist[tid] = 0;
  // init stage to self-node id: pad slots become valid self rows, and slot
  // cnt (first un-filled) supplies the GIN self term.
  for (int i = tid; i < 128 * MAXDEG; i += 512) stage[i] = (b << BSH) + (i >> 6);
  __syncthreads();
  int n = gCnt[b];
  if (n > BCAP) n = BCAP;
  const unsigned* eb = ebuf + (size_t)b * BCAP;
  for (int i = tid; i < n; i += 512) {
    unsigned pk = eb[i];
    int dloc = (int)(pk >> 17);
    int slot = atomicAdd(&hist[dloc], 1);
    if (slot < MAXDEG) stage[(dloc << 6) + slot] = (int)(pk & 0x1FFFFu);
  }
  __syncthreads();
  if (tid < 128) {
    int gnode = (b << BSH) + tid;
    if (gnode < N_NODES) cnt[gnode] = hist[tid];
  }
  if (tid < 8) {  // per-16-node-group max effective degree (dE = min(d,63)+1)
    int mx = 1;
#pragma unroll
    for (int k = 0; k < 16; ++k) {
      int d = hist[tid * 16 + k];
      if (d > 63) d = 63;
      if (d + 1 > mx) mx = d + 1;
    }
    gmax[(b << 3) + tid] = mx;
  }
  const int4* st4 = (const int4*)stage;
  int4* dst4 = (int4*)(csr + (size_t)b * (128 * MAXDEG));
  for (int i = tid; i < 128 * MAXDEG / 4; i += 512) dst4[i] = st4[i];
}

// ---------------- xcvt: x (fp32 [N,7]) -> xc (bf16 [N,8], pad dim7 = 0) ----------------
__global__ __launch_bounds__(256) void xcvt_kernel(const float* __restrict__ x,
                                                   unsigned* __restrict__ xc) {
  int i = blockIdx.x * 256 + threadIdx.x;
  if (i >= N_NODES * 4) return;
  int n = i >> 2, p = i & 3;
  float lo = x[n * 7 + 2 * p];
  float hi = (2 * p + 1 < 7) ? x[n * 7 + 2 * p + 1] : 0.f;
  xc[i] = bf16_rne(lo) | (bf16_rne(hi) << 16);
}

// ---------------- conv1 (7->32): TRANSPOSED gather (proven R10) ----------------
__global__ __launch_bounds__(256) void gin1(
    const unsigned short* __restrict__ xc16, const int* __restrict__ cnt,
    const int* __restrict__ csr, const int* __restrict__ gmax,
    const float* __restrict__ W1, const float* __restrict__ b1,
    const float* __restrict__ W2, const float* __restrict__ b2,
    const float* __restrict__ gamma, const float* __restrict__ beta,
    const float* __restrict__ mean, const float* __restrict__ var,
    unsigned short* __restrict__ hout16) {
  __shared__ __align__(16) float zs[4][16][12];   // stride 12: 2-way max on writes
  __shared__ __align__(16) float ts[4][32];
  int tid = threadIdx.x;
  int w = __builtin_amdgcn_readfirstlane(tid >> 6);
  int lane = tid & 63;
  int nl = lane & 15;    // node within group
  int c  = lane >> 4;    // 4-B chunk = dims [2c, 2c+1]
  int half = lane >> 5, j = lane & 31;  // MLP roles

  float wr1[4], wr2[16];
#pragma unroll
  for (int i = 0; i < 4; ++i) {
    int k = half * 4 + i;
    wr1[i] = (k < 7) ? W1[k * 32 + j] : 0.f;
  }
#pragma unroll
  for (int i = 0; i < 16; ++i) wr2[i] = W2[(half * 16 + i) * 32 + j];
  float vb1 = b1[j], vb2 = b2[j];
  float sc = gamma[j] * rsqrtf(var[j] + BN_EPS);
  float sh = beta[j] - mean[j] * sc;

  const unsigned* xc32 = (const unsigned*)xc16;  // 4 x unsigned per 16-B row

  const int NW = gridDim.x * 4;
  for (int g = blockIdx.x * 4 + w; g < NGRP; g += NW) {
    int node = g * 16 + nl;
    int dcnt = cnt[node];
    if (dcnt > 63) dcnt = 63;
    int dE = dcnt + 1;  // edges + self (slot dcnt = self via b2 init)
    int dmax = __builtin_amdgcn_readfirstlane(gmax[g]);
    int nb = (dmax + 3) >> 2;

    const int* crow = csr + (size_t)node * MAXDEG;
    float a0 = 0.f, a1 = 0.f;

    uint4 i4 = *(const uint4*)crow;   // slots 0..3
    for (int b = 0; b < nb; ++b) {
      uint4 i4n = i4;
      if (b + 1 < nb) i4n = *(const uint4*)(crow + (b + 1) * 4);
      unsigned v0 = xc32[(size_t)i4.x * 4 + c];
      unsigned v1 = xc32[(size_t)i4.y * 4 + c];
      unsigned v2 = xc32[(size_t)i4.z * 4 + c];
      unsigned v3 = xc32[(size_t)i4.w * 4 + c];
      int s0 = b * 4;
      if (s0 + 0 < dE) { a0 += bf_lo(v0); a1 += bf_hi(v0); }
      if (s0 + 1 < dE) { a0 += bf_lo(v1); a1 += bf_hi(v1); }
      if (s0 + 2 < dE) { a0 += bf_lo(v2); a1 += bf_hi(v2); }
      if (s0 + 3 < dE) { a0 += bf_lo(v3); a1 += bf_hi(v3); }
      i4 = i4n;
    }

    // deposit z: lane (nl,c) owns dims [2c, 2c+1] of node nl
    {
      float2 z0 = {a0, a1};
      *(float2*)&zs[w][nl][c * 2] = z0;
    }

    // ---- per-node MLP x16 (proven gin1 MLP, z from zs) ----
    for (int p = 0; p < 16; ++p) {
      int np = g * 16 + p;
      float tp = half ? 0.f : vb1;
      {
        const float4* zp = (const float4*)&zs[w][p][half * 4];
        float4 z0 = zp[0];
        tp = fmaf(z0.x, wr1[0], tp); tp = fmaf(z0.y, wr1[1], tp);
        tp = fmaf(z0.z, wr1[2], tp); tp = fmaf(z0.w, wr1[3], tp);
      }
      tp += __shfl_xor(tp, 32);
      tp = fmaxf(tp, 0.f);
      if (!half) ts[w][j] = tp;

      float op = half ? 0.f : vb2;
      {
        const float4* tpp = (const float4*)&ts[w][half * 16];
        float4 t0 = tpp[0], t1 = tpp[1], t2 = tpp[2], t3 = tpp[3];
        op = fmaf(t0.x, wr2[0], op);  op = fmaf(t0.y, wr2[1], op);
        op = fmaf(t0.z, wr2[2], op);  op = fmaf(t0.w, wr2[3], op);
        op = fmaf(t1.x, wr2[4], op);  op = fmaf(t1.y, wr2[5], op);
        op = fmaf(t1.z, wr2[6], op);  op = fmaf(t1.w, wr2[7], op);
        op = fmaf(t2.x, wr2[8], op);  op = fmaf(t2.y, wr2[9], op);
        op = fmaf(t2.z, wr2[10], op); op = fmaf(t2.w, wr2[11], op);
        op = fmaf(t3.x, wr2[12], op); op = fmaf(t3.y, wr2[13], op);
        op = fmaf(t3.z, wr2[14], op); op = fmaf(t3.w, wr2[15], op);
      }
      op += __shfl_xor(op, 32);
      if (!half) {
        op = fmaxf(op, 0.f) * sc + sh;
        float hi = __shfl(op, j | 1);
        if ((j & 1) == 0) {
          unsigned pk = bf16_rne(op) | (bf16_rne(hi) << 16);
          ((unsigned*)hout16)[np * 16 + (j >> 1)] = pk;
        }
      }
    }
  }
}

// ---------------- conv2..5: transposed gather + DOUBLE-SPLIT MFMA MLP (R13) ----------------
// R12 post-mortem: A-split changed nothing -> W bf16 rounding dominates.
// Now BOTH operands split hi/lo. Each GEMM = 3 chained MFMAs:
//   D = A_hi@W_hi + A_lo@W_hi + A_hi@W_lo   (lo@lo ~2^-18, dropped)
// -> effective fp32-grade GEMM; residual error = h/output bf16 storage only
// (same as the passing non-MFMA baseline).
__global__ __launch_bounds__(256) void gin_layer32(
    const unsigned short* __restrict__ hin16, const int* __restrict__ cnt,
    const int* __restrict__ csr, const int* __restrict__ gmax,
    const float* __restrict__ W1, const float* __restrict__ b1,
    const float* __restrict__ W2, const float* __restrict__ b2,
    const float* __restrict__ gamma, const float* __restrict__ beta,
    const float* __restrict__ mean, const float* __restrict__ var,
    unsigned short* __restrict__ hout16) {
  __shared__ __align__(16) float ts[4][16][36];   // 9.2 KB transpose buffer
  int tid = threadIdx.x;
  int w = __builtin_amdgcn_readfirstlane(tid >> 6);  // wave id, force-scalar
  int lane = tid & 63;
  int nl = lane & 15;    // node within group (A row / B,D col)
  int q  = lane >> 4;    // k-block (A) / row-block (D)

  // B fragments split hi/lo: lane holds W[k=8q+i][col nl] and [col 16+nl]
  bf16x8 w1ah, w1al, w1bh, w1bl, w2ah, w2al, w2bh, w2bl;
#pragma unroll
  for (int i = 0; i < 8; ++i) {
    float f;
    __bf16 h;
    f = W1[(q * 8 + i) * 32 + nl];       h = (__bf16)f;
    w1ah[i] = h; w1al[i] = (__bf16)(f - (float)h);
    f = W1[(q * 8 + i) * 32 + 16 + nl];  h = (__bf16)f;
    w1bh[i] = h; w1bl[i] = (__bf16)(f - (float)h);
    f = W2[(q * 8 + i) * 32 + nl];       h = (__bf16)f;
    w2ah[i] = h; w2al[i] = (__bf16)(f - (float)h);
    f = W2[(q * 8 + i) * 32 + 16 + nl];  h = (__bf16)f;
    w2bh[i] = h; w2bl[i] = (__bf16)(f - (float)h);
  }
  // bias C-inits (bias depends only on col n = nl / 16+nl; same for all rows)
  float vb1a = b1[nl], vb1b = b1[16 + nl];
  float vb2a = b2[nl], vb2b = b2[16 + nl];
  f32x4 cb1a = {vb1a, vb1a, vb1a, vb1a};
  f32x4 cb1b = {vb1b, vb1b, vb1b, vb1b};
  f32x4 cb2a = {vb2a, vb2a, vb2a, vb2a};
  f32x4 cb2b = {vb2b, vb2b, vb2b, vb2b};
  // bn per output dim (col)
  float sc0 = gamma[nl] * rsqrtf(var[nl] + BN_EPS);
  float sh0 = beta[nl] - mean[nl] * sc0;
  float sc1 = gamma[16 + nl] * rsqrtf(var[16 + nl] + BN_EPS);
  float sh1 = beta[16 + nl] - mean[16 + nl] * sc1;

  const int NW = gridDim.x * 4;
  for (int g = blockIdx.x * 4 + w; g < NGRP; g += NW) {
    int node = g * 16 + nl;
    int dcnt = cnt[node];
    if (dcnt > 63) dcnt = 63;
    int dE = dcnt + 1;  // edges + self (self at slot dcnt via b2 init)
    int dmax = __builtin_amdgcn_readfirstlane(gmax[g]);
    int nb = (dmax + 3) >> 2;

    const int* crow = csr + (size_t)node * MAXDEG;
    float acc[8];
#pragma unroll
    for (int i = 0; i < 8; ++i) acc[i] = 0.f;

    uint4 i4 = *(const uint4*)crow;   // slots 0..3
    for (int b = 0; b < nb; ++b) {
      uint4 i4n = i4;
      if (b + 1 < nb) i4n = *(const uint4*)(crow + (b + 1) * 4);
      uint4 v0 = *(const uint4*)(hin16 + (size_t)i4.x * 32 + q * 8);
      uint4 v1 = *(const uint4*)(hin16 + (size_t)i4.y * 32 + q * 8);
      uint4 v2 = *(const uint4*)(hin16 + (size_t)i4.z * 32 + q * 8);
      uint4 v3 = *(const uint4*)(hin16 + (size_t)i4.w * 32 + q * 8);
      int s0 = b * 4;
      if (s0 + 0 < dE) {
        acc[0] += bf_lo(v0.x); acc[1] += bf_hi(v0.x);
        acc[2] += bf_lo(v0.y); acc[3] += bf_hi(v0.y);
        acc[4] += bf_lo(v0.z); acc[5] += bf_hi(v0.z);
        acc[6] += bf_lo(v0.w); acc[7] += bf_hi(v0.w);
      }
      if (s0 + 1 < dE) {
        acc[0] += bf_lo(v1.x); acc[1] += bf_hi(v1.x);
        acc[2] += bf_lo(v1.y); acc[3] += bf_hi(v1.y);
        acc[4] += bf_lo(v1.z); acc[5] += bf_hi(v1.z);
        acc[6] += bf_lo(v1.w); acc[7] += bf_hi(v1.w);
      }
      if (s0 + 2 < dE) {
        acc[0] += bf_lo(v2.x); acc[1] += bf_hi(v2.x);
        acc[2] += bf_lo(v2.y); acc[3] += bf_hi(v2.y);
        acc[4] += bf_lo(v2.z); acc[5] += bf_hi(v2.z);
        acc[6] += bf_lo(v2.w); acc[7] += bf_hi(v2.w);
      }
      if (s0 + 3 < dE) {
        acc[0] += bf_lo(v3.x); acc[1] += bf_hi(v3.x);
        acc[2] += bf_lo(v3.y); acc[3] += bf_hi(v3.y);
        acc[4] += bf_lo(v3.z); acc[5] += bf_hi(v3.z);
        acc[6] += bf_lo(v3.w); acc[7] += bf_hi(v3.w);
      }
      i4 = i4n;
    }

    // ---- A fragment split hi/lo (layout matches accumulators exactly) ----
    bf16x8 af, afl;
#pragma unroll
    for (int i = 0; i < 8; ++i) {
      __bf16 h = (__bf16)acc[i];
      af[i] = h;
      afl[i] = (__bf16)(acc[i] - (float)h);
    }

    // ---- layer 1: T = relu(Z @ W1 + b1), 3 chained MFMAs per half ----
    f32x4 t0 = __builtin_amdgcn_mfma_f32_16x16x32_bf16(af,  w1ah, cb1a, 0, 0, 0);
    t0 = __builtin_amdgcn_mfma_f32_16x16x32_bf16(afl, w1ah, t0, 0, 0, 0);
    t0 = __builtin_amdgcn_mfma_f32_16x16x32_bf16(af,  w1al, t0, 0, 0, 0);
    f32x4 t1 = __builtin_amdgcn_mfma_f32_16x16x32_bf16(af,  w1bh, cb1b, 0, 0, 0);
    t1 = __builtin_amdgcn_mfma_f32_16x16x32_bf16(afl, w1bh, t1, 0, 0, 0);
    t1 = __builtin_amdgcn_mfma_f32_16x16x32_bf16(af,  w1bl, t1, 0, 0, 0);
#pragma unroll
    for (int r = 0; r < 4; ++r) {
      t0[r] = fmaxf(t0[r], 0.f);
      t1[r] = fmaxf(t1[r], 0.f);
    }
    // transpose D -> A2 via LDS (in-wave, DS ops are in-order within a wave)
#pragma unroll
    for (int r = 0; r < 4; ++r) {
      ts[w][q * 4 + r][nl]      = t0[r];
      ts[w][q * 4 + r][16 + nl] = t1[r];
    }
    bf16x8 af2, af2l;
    {
      float4 r0 = *(const float4*)&ts[w][nl][q * 8];
      float4 r1 = *(const float4*)&ts[w][nl][q * 8 + 4];
      float tv[8] = {r0.x, r0.y, r0.z, r0.w, r1.x, r1.y, r1.z, r1.w};
#pragma unroll
      for (int i = 0; i < 8; ++i) {
        __bf16 h = (__bf16)tv[i];
        af2[i] = h;
        af2l[i] = (__bf16)(tv[i] - (float)h);
      }
    }

    // ---- layer 2: O = bn(relu(T @ W2 + b2)), 3 chained MFMAs per half ----
    f32x4 o0 = __builtin_amdgcn_mfma_f32_16x16x32_bf16(af2,  w2ah, cb2a, 0, 0, 0);
    o0 = __builtin_amdgcn_mfma_f32_16x16x32_bf16(af2l, w2ah, o0, 0, 0, 0);
    o0 = __builtin_amdgcn_mfma_f32_16x16x32_bf16(af2,  w2al, o0, 0, 0, 0);
    f32x4 o1 = __builtin_amdgcn_mfma_f32_16x16x32_bf16(af2,  w2bh, cb2b, 0, 0, 0);
    o1 = __builtin_amdgcn_mfma_f32_16x16x32_bf16(af2l, w2bh, o1, 0, 0, 0);
    o1 = __builtin_amdgcn_mfma_f32_16x16x32_bf16(af2,  w2bl, o1, 0, 0, 0);
#pragma unroll
    for (int r = 0; r < 4; ++r) {
      o0[r] = fmaxf(o0[r], 0.f) * sc0 + sh0;
      o1[r] = fmaxf(o1[r], 0.f) * sc1 + sh1;
    }
    // transpose D -> row-major, pack bf16 pairs, coalesced uint4 store
#pragma unroll
    for (int r = 0; r < 4; ++r) {
      ts[w][q * 4 + r][nl]      = o0[r];
      ts[w][q * 4 + r][16 + nl] = o1[r];
    }
    {
      float4 f0 = *(const float4*)&ts[w][nl][q * 8];
      float4 f1 = *(const float4*)&ts[w][nl][q * 8 + 4];
      uint4 st;
      st.x = bf16_rne(f0.x) | (bf16_rne(f0.y) << 16);
      st.y = bf16_rne(f0.z) | (bf16_rne(f0.w) << 16);
      st.z = bf16_rne(f1.x) | (bf16_rne(f1.y) << 16);
      st.w = bf16_rne(f1.z) | (bf16_rne(f1.w) << 16);
      *(uint4*)(hout16 + (size_t)node * 32 + q * 8) = st;
    }
  }
}

// ---------------- pool: one block per graph (batch sorted), bf16 in ----------------
__global__ __launch_bounds__(256) void pool_kernel(const unsigned short* __restrict__ h16,
                                                   const int* __restrict__ batch,
                                                   float* __restrict__ g) {
  __shared__ int s_lo, s_hi;
  __shared__ float red[8][33];
  int gr = blockIdx.x;
  if (threadIdx.x == 0) {
    int lo = 0, hi = N_NODES;
    while (lo < hi) { int m = (lo + hi) >> 1; if (batch[m] < gr) lo = m + 1; else hi = m; }
    s_lo = lo;
  } else if (threadIdx.x == 1) {
    int lo = 0, hi = N_NODES;
    while (lo < hi) { int m = (lo + hi) >> 1; if (batch[m] < gr + 1) lo = m + 1; else hi = m; }
    s_hi = lo;
  }
  __syncthreads();
  int lo = s_lo, hi = s_hi;
  int j = threadIdx.x & 31;
  int nd = threadIdx.x >> 5;
  float acc = 0.f;
  for (int n = lo + nd; n < hi; n += 8)
    acc += __uint_as_float((unsigned)h16[n * 32 + j] << 16);
  red[nd][j] = acc;
  __syncthreads();
  if (threadIdx.x < 32) {
    float s = 0.f;
#pragma unroll
    for (int r = 0; r < 8; ++r) s += red[r][j];
    g[gr * 32 + j] = s;
  }
}

// ---------------- head (fp32) ----------------
__global__ __launch_bounds__(256) void head_kernel(
    const float* __restrict__ g, const float* __restrict__ W1, const float* __restrict__ b1,
    const float* __restrict__ W2, const float* __restrict__ b2, float* __restrict__ out) {
  __shared__ float sW1[1024], sb1[32];
  __shared__ float sW2[64], sb2[2];
  __shared__ float zb[8][33], tb[8][33], lb[8][2];
  int tid = threadIdx.x;
  for (int i = tid; i < 1024; i += 256) sW1[i] = W1[i];
  if (tid < 64) sW2[tid] = W2[tid];
  if (tid < 32) sb1[tid] = b1[tid];
  if (tid < 2) sb2[tid] = b2[tid];
  int nd = tid >> 5;
  int gr = blockIdx.x * 8 + nd;
  int j = tid & 31;
  __syncthreads();
  float z = (gr < N_GRAPHS) ? g[gr * 32 + j] : 0.f;
  zb[nd][j] = z;
  __syncthreads();
  float t = sb1[j];
#pragma unroll
  for (int k = 0; k < 32; ++k) t = fmaf(zb[nd][k], sW1[k * 32 + j], t);
  t = fmaxf(t, 0.f);
  tb[nd][j] = t;
  __syncthreads();
  if (j < 2) {
    float l = sb2[j];
#pragma unroll
    for (int k = 0; k < 32; ++k) l = fmaf(tb[nd][k], sW2[k * 2 + j], l);
    lb[nd][j] = l;
  }
  __syncthreads();
  if (gr < N_GRAPHS && j < 2) {
    float l0 = lb[nd][0], l1 = lb[nd][1];
    float m = fmaxf(l0, l1);
    float lse = m + logf(expf(l0 - m) + expf(l1 - m));
    out[gr * 2 + j] = lb[nd][j] - lse;
  }
}

extern "C" void kernel_launch(void* const* d_in, const int* in_sizes, int n_in,
                              void* d_out, int out_size, void* d_ws, size_t ws_size,
                              hipStream_t stream) {
  const float* x     = (const float*)d_in[0];
  const int*   eidx  = (const int*)d_in[1];
  const int*   batch = (const int*)d_in[2];
  const float* c1W1  = (const float*)d_in[3];
  const float* c1b1  = (const float*)d_in[4];
  const float* c1W2  = (const float*)d_in[5];
  const float* c1b2  = (const float*)d_in[6];
  const float* csW1  = (const float*)d_in[7];
  const float* csb1  = (const float*)d_in[8];
  const float* csW2  = (const float*)d_in[9];
  const float* csb2  = (const float*)d_in[10];
  const float* bng   = (const float*)d_in[11];
  const float* bnb   = (const float*)d_in[12];
  const float* bnm   = (const float*)d_in[13];
  const float* bnv   = (const float*)d_in[14];
  const float* fc1W  = (const float*)d_in[15];
  const float* fc1b  = (const float*)d_in[16];
  const float* fc2W  = (const float*)d_in[17];
  const float* fc2b  = (const float*)d_in[18];
  float* out = (float*)d_out;

  const int* src = eidx;
  const int* dst = eidx + N_EDGES;

  // workspace (~50.3 MB)
  char* p = (char*)d_ws;
  unsigned short* hA16 = (unsigned short*)p; p += (size_t)N_NODES * 32 * 2;   // 6.4 MB
  unsigned short* hB16 = (unsigned short*)p; p += (size_t)N_NODES * 32 * 2;   // 6.4 MB
  int*      cnt  = (int*)p;      p += (size_t)N_NODES * 4;                    // 0.4 MB
  int*      csr  = (int*)p;      p += (size_t)NBKT * 128 * MAXDEG * 4;        // 25.6 MB
  unsigned* ebuf = (unsigned*)p; p += (size_t)NBKT * BCAP * 4;                // 11.2 MB
  int*      gCur = (int*)p;      p += 1024 * 4;
  int*      gmax = (int*)p;      p += (size_t)(NBKT * 8) * 4;                 // 25 KB
  float*    g    = (float*)p;    p += (size_t)N_GRAPHS * 32 * 4;
  // xc (bf16 [N,8], 1.6 MB) aliases ebuf: ebuf is dead after b2_csr completes
  unsigned* xc = ebuf;

  // ---- build: bucket pass + per-bucket padded-CSR pass ----
  (void)hipMemsetAsync(gCur, 0, 1024 * 4, stream);
  b1_bucket<<<(N_EDGES + E_PER_BLK - 1) / E_PER_BLK, 1024, 0, stream>>>(src, dst, gCur, ebuf);
  b2_csr<<<NBKT, 512, 0, stream>>>(ebuf, gCur, cnt, csr, gmax);

  // ---- x -> bf16 padded rows (after b2: xc aliases ebuf) ----
  xcvt_kernel<<<(N_NODES * 4 + 255) / 256, 256, 0, stream>>>(x, xc);

  // ---- conv1 (7->32) + relu + bn0, transposed gather ----
  gin1<<<(NGRP + 3) / 4, 256, 0, stream>>>(
      (const unsigned short*)xc, cnt, csr, gmax, c1W1, c1b1, c1W2, c1b2,
      bng, bnb, bnm, bnv, hA16);

  // ---- conv2..5 (32->32) + relu + bn1..4, transposed gather + split MFMA MLP ----
  unsigned short* cur = hA16;
  unsigned short* nxt = hB16;
  for (int i = 0; i < 4; ++i) {
    gin_layer32<<<(NGRP + 3) / 4, 256, 0, stream>>>(
        cur, cnt, csr, gmax,
        csW1 + (size_t)i * 1024, csb1 + (size_t)i * 32,
        csW2 + (size_t)i * 1024, csb2 + (size_t)i * 32,
        bng + (size_t)(i + 1) * 32, bnb + (size_t)(i + 1) * 32,
        bnm + (size_t)(i + 1) * 32, bnv + (size_t)(i + 1) * 32, nxt);
    unsigned short* tmp = cur; cur = nxt; nxt = tmp;
  }

  pool_kernel<<<N_GRAPHS, 256, 0, stream>>>(cur, batch, g);
  head_kernel<<<(N_GRAPHS + 7) / 8, 256, 0, stream>>>(g, fc1W, fc1b, fc2W, fc2b, out);
}

// Round 15
// 295.949 us; speedup vs baseline: 1.2916x; 1.0582x over previous
//
#include <hip/hip_runtime.h>

#define N_NODES  100000
#define N_EDGES  2000000
#define N_GRAPHS 1000
#define NFEAT    7
#define BN_EPS   1e-5f
#define MAXDEG   64    // in-degree ~ Poisson(20); P(max over 100k > 63) < 1e-9

#define BSH      7     // 128-node dst buckets
#define NBKT     782   // ceil(100000/128)
#define BCAP     3584  // per-bucket edge cap: mean 2560 + 20 sigma
#define E_PER_BLK 4096
#define NGRP     6250  // 100000/16 node groups

// bf16 helpers (storage only; arithmetic fp32 unless noted)
__device__ __forceinline__ unsigned bf16_rne(float f) {
  unsigned u = __float_as_uint(f);
  return (u + 0x7FFFu + ((u >> 16) & 1u)) >> 16;
}
__device__ __forceinline__ float bf_lo(unsigned u) { return __uint_as_float(u << 16); }
__device__ __forceinline__ float bf_hi(unsigned u) { return __uint_as_float(u & 0xFFFF0000u); }

// MFMA fragment types (gfx950)
typedef __bf16 bf16x8 __attribute__((ext_vector_type(8)));
typedef float  f32x4  __attribute__((ext_vector_type(4)));

// ---------------- b1: bucket edges by dst>>7, block-contiguous writes ----------------
__global__ __launch_bounds__(1024) void b1_bucket(const int* __restrict__ src,
                                                  const int* __restrict__ dst,
                                                  int* __restrict__ gCur,
                                                  unsigned* __restrict__ ebuf) {
  __shared__ int hist[NBKT], base[NBKT];
  int tid = threadIdx.x;
  for (int i = tid; i < NBKT; i += 1024) hist[i] = 0;
  __syncthreads();
  unsigned pk[4];
  int bo[4];
  int e0 = blockIdx.x * E_PER_BLK;
#pragma unroll
  for (int k = 0; k < 4; ++k) {
    int e = e0 + k * 1024 + tid;
    if (e < N_EDGES) {
      int d = dst[e], s = src[e];
      int b = d >> BSH;
      int off = atomicAdd(&hist[b], 1);
      pk[k] = ((unsigned)(d & 127) << 17) | (unsigned)s;
      bo[k] = (b << 17) | off;
    } else {
      bo[k] = -1;
    }
  }
  __syncthreads();
  for (int i = tid; i < NBKT; i += 1024)
    base[i] = hist[i] ? atomicAdd(&gCur[i], hist[i]) : 0;
  __syncthreads();
#pragma unroll
  for (int k = 0; k < 4; ++k) {
    if (bo[k] >= 0) {
      int b = bo[k] >> 17, off = bo[k] & 0x1FFFF;
      int p = base[b] + off;
      if (p < BCAP) ebuf[(size_t)b * BCAP + p] = pk[k];
    }
  }
}

// ---------------- b2: one block per bucket -> padded csr (pad=self) + cnt + gmax ----------------
__global__ __launch_bounds__(512) void b2_csr(const unsigned* __restrict__ ebuf,
                                              const int* __restrict__ gCnt,
                                              int* __restrict__ cnt,
                                              int* __restrict__ csr,
                                              int* __restrict__ gmax) {
  __shared__ int hist[128];
  __shared__ int stage[128 * MAXDEG];
  int b = blockIdx.x, tid = threadIdx.x;
  if (tid < 128) hist[tid] = 0;
  // init stage to self-node id: pad slots become valid self rows, and slot
  // cnt (first un-filled) supplies the GIN self term.
  for (int i = tid; i < 128 * MAXDEG; i += 512) stage[i] = (b << BSH) + (i >> 6);
  __syncthreads();
  int n = gCnt[b];
  if (n > BCAP) n = BCAP;
  const unsigned* eb = ebuf + (size_t)b * BCAP;
  for (int i = tid; i < n; i += 512) {
    unsigned pk = eb[i];
    int dloc = (int)(pk >> 17);
    int slot = atomicAdd(&hist[dloc], 1);
    if (slot < MAXDEG) stage[(dloc << 6) + slot] = (int)(pk & 0x1FFFFu);
  }
  __syncthreads();
  if (tid < 128) {
    int gnode = (b << BSH) + tid;
    if (gnode < N_NODES) cnt[gnode] = hist[tid];
  }
  if (tid < 8) {  // per-16-node-group max effective degree (dE = min(d,63)+1)
    int mx = 1;
#pragma unroll
    for (int k = 0; k < 16; ++k) {
      int d = hist[tid * 16 + k];
      if (d > 63) d = 63;
      if (d + 1 > mx) mx = d + 1;
    }
    gmax[(b << 3) + tid] = mx;
  }
  const int4* st4 = (const int4*)stage;
  int4* dst4 = (int4*)(csr + (size_t)b * (128 * MAXDEG));
  for (int i = tid; i < 128 * MAXDEG / 4; i += 512) dst4[i] = st4[i];
}

// ---------------- xcvt: x (fp32 [N,7]) -> xc (bf16 [N,8], pad dim7 = 0) ----------------
__global__ __launch_bounds__(256) void xcvt_kernel(const float* __restrict__ x,
                                                   unsigned* __restrict__ xc) {
  int i = blockIdx.x * 256 + threadIdx.x;
  if (i >= N_NODES * 4) return;
  int n = i >> 2, p = i & 3;
  float lo = x[n * 7 + 2 * p];
  float hi = (2 * p + 1 < 7) ? x[n * 7 + 2 * p + 1] : 0.f;
  xc[i] = bf16_rne(lo) | (bf16_rne(hi) << 16);
}

// ---------------- conv1 (7->32): TRANSPOSED gather (proven R10) ----------------
__global__ __launch_bounds__(256) void gin1(
    const unsigned short* __restrict__ xc16, const int* __restrict__ cnt,
    const int* __restrict__ csr, const int* __restrict__ gmax,
    const float* __restrict__ W1, const float* __restrict__ b1,
    const float* __restrict__ W2, const float* __restrict__ b2,
    const float* __restrict__ gamma, const float* __restrict__ beta,
    const float* __restrict__ mean, const float* __restrict__ var,
    unsigned short* __restrict__ hout16) {
  __shared__ __align__(16) float zs[4][16][12];   // stride 12: 2-way max on writes
  __shared__ __align__(16) float ts[4][32];
  int tid = threadIdx.x;
  int w = __builtin_amdgcn_readfirstlane(tid >> 6);
  int lane = tid & 63;
  int nl = lane & 15;    // node within group
  int c  = lane >> 4;    // 4-B chunk = dims [2c, 2c+1]
  int half = lane >> 5, j = lane & 31;  // MLP roles

  float wr1[4], wr2[16];
#pragma unroll
  for (int i = 0; i < 4; ++i) {
    int k = half * 4 + i;
    wr1[i] = (k < 7) ? W1[k * 32 + j] : 0.f;
  }
#pragma unroll
  for (int i = 0; i < 16; ++i) wr2[i] = W2[(half * 16 + i) * 32 + j];
  float vb1 = b1[j], vb2 = b2[j];
  float sc = gamma[j] * rsqrtf(var[j] + BN_EPS);
  float sh = beta[j] - mean[j] * sc;

  const unsigned* xc32 = (const unsigned*)xc16;  // 4 x unsigned per 16-B row

  const int NW = gridDim.x * 4;
  for (int g = blockIdx.x * 4 + w; g < NGRP; g += NW) {
    int node = g * 16 + nl;
    int dcnt = cnt[node];
    if (dcnt > 63) dcnt = 63;
    int dE = dcnt + 1;  // edges + self (slot dcnt = self via b2 init)
    int dmax = __builtin_amdgcn_readfirstlane(gmax[g]);
    int nb = (dmax + 3) >> 2;

    const int* crow = csr + (size_t)node * MAXDEG;
    float a0 = 0.f, a1 = 0.f;

    uint4 i4 = *(const uint4*)crow;   // slots 0..3
    for (int b = 0; b < nb; ++b) {
      uint4 i4n = i4;
      if (b + 1 < nb) i4n = *(const uint4*)(crow + (b + 1) * 4);
      unsigned v0 = xc32[(size_t)i4.x * 4 + c];
      unsigned v1 = xc32[(size_t)i4.y * 4 + c];
      unsigned v2 = xc32[(size_t)i4.z * 4 + c];
      unsigned v3 = xc32[(size_t)i4.w * 4 + c];
      int s0 = b * 4;
      if (s0 + 0 < dE) { a0 += bf_lo(v0); a1 += bf_hi(v0); }
      if (s0 + 1 < dE) { a0 += bf_lo(v1); a1 += bf_hi(v1); }
      if (s0 + 2 < dE) { a0 += bf_lo(v2); a1 += bf_hi(v2); }
      if (s0 + 3 < dE) { a0 += bf_lo(v3); a1 += bf_hi(v3); }
      i4 = i4n;
    }

    // deposit z: lane (nl,c) owns dims [2c, 2c+1] of node nl
    {
      float2 z0 = {a0, a1};
      *(float2*)&zs[w][nl][c * 2] = z0;
    }

    // ---- per-node MLP x16 (proven gin1 MLP, z from zs) ----
    for (int p = 0; p < 16; ++p) {
      int np = g * 16 + p;
      float tp = half ? 0.f : vb1;
      {
        const float4* zp = (const float4*)&zs[w][p][half * 4];
        float4 z0 = zp[0];
        tp = fmaf(z0.x, wr1[0], tp); tp = fmaf(z0.y, wr1[1], tp);
        tp = fmaf(z0.z, wr1[2], tp); tp = fmaf(z0.w, wr1[3], tp);
      }
      tp += __shfl_xor(tp, 32);
      tp = fmaxf(tp, 0.f);
      if (!half) ts[w][j] = tp;

      float op = half ? 0.f : vb2;
      {
        const float4* tpp = (const float4*)&ts[w][half * 16];
        float4 t0 = tpp[0], t1 = tpp[1], t2 = tpp[2], t3 = tpp[3];
        op = fmaf(t0.x, wr2[0], op);  op = fmaf(t0.y, wr2[1], op);
        op = fmaf(t0.z, wr2[2], op);  op = fmaf(t0.w, wr2[3], op);
        op = fmaf(t1.x, wr2[4], op);  op = fmaf(t1.y, wr2[5], op);
        op = fmaf(t1.z, wr2[6], op);  op = fmaf(t1.w, wr2[7], op);
        op = fmaf(t2.x, wr2[8], op);  op = fmaf(t2.y, wr2[9], op);
        op = fmaf(t2.z, wr2[10], op); op = fmaf(t2.w, wr2[11], op);
        op = fmaf(t3.x, wr2[12], op); op = fmaf(t3.y, wr2[13], op);
        op = fmaf(t3.z, wr2[14], op); op = fmaf(t3.w, wr2[15], op);
      }
      op += __shfl_xor(op, 32);
      if (!half) {
        op = fmaxf(op, 0.f) * sc + sh;
        float hi = __shfl(op, j | 1);
        if ((j & 1) == 0) {
          unsigned pk = bf16_rne(op) | (bf16_rne(hi) << 16);
          ((unsigned*)hout16)[np * 16 + (j >> 1)] = pk;
        }
      }
    }
  }
}

// ---------------- conv2..5: pipelined transposed gather + double-split MFMA MLP (R15) ----------------
// R14 (passing) + one-batch-deep gather pipeline: rows prefetched one batch
// ahead (idx two ahead); accumulate of batch b overlaps batch b+1's loads.
__global__ __launch_bounds__(256) void gin_layer32(
    const unsigned short* __restrict__ hin16, const int* __restrict__ cnt,
    const int* __restrict__ csr, const int* __restrict__ gmax,
    const float* __restrict__ W1, const float* __restrict__ b1,
    const float* __restrict__ W2, const float* __restrict__ b2,
    const float* __restrict__ gamma, const float* __restrict__ beta,
    const float* __restrict__ mean, const float* __restrict__ var,
    unsigned short* __restrict__ hout16) {
  __shared__ __align__(16) float ts[4][16][36];   // 9.2 KB transpose buffer
  int tid = threadIdx.x;
  int w = __builtin_amdgcn_readfirstlane(tid >> 6);  // wave id, force-scalar
  int lane = tid & 63;
  int nl = lane & 15;    // node within group (A row / B,D col)
  int q  = lane >> 4;    // k-block (A) / row-block (D)

  // B fragments split hi/lo: lane holds W[k=8q+i][col nl] and [col 16+nl]
  bf16x8 w1ah, w1al, w1bh, w1bl, w2ah, w2al, w2bh, w2bl;
#pragma unroll
  for (int i = 0; i < 8; ++i) {
    float f;
    __bf16 h;
    f = W1[(q * 8 + i) * 32 + nl];       h = (__bf16)f;
    w1ah[i] = h; w1al[i] = (__bf16)(f - (float)h);
    f = W1[(q * 8 + i) * 32 + 16 + nl];  h = (__bf16)f;
    w1bh[i] = h; w1bl[i] = (__bf16)(f - (float)h);
    f = W2[(q * 8 + i) * 32 + nl];       h = (__bf16)f;
    w2ah[i] = h; w2al[i] = (__bf16)(f - (float)h);
    f = W2[(q * 8 + i) * 32 + 16 + nl];  h = (__bf16)f;
    w2bh[i] = h; w2bl[i] = (__bf16)(f - (float)h);
  }
  // bias C-inits (bias depends only on col n = nl / 16+nl; same for all rows)
  float vb1a = b1[nl], vb1b = b1[16 + nl];
  float vb2a = b2[nl], vb2b = b2[16 + nl];
  f32x4 cb1a = {vb1a, vb1a, vb1a, vb1a};
  f32x4 cb1b = {vb1b, vb1b, vb1b, vb1b};
  f32x4 cb2a = {vb2a, vb2a, vb2a, vb2a};
  f32x4 cb2b = {vb2b, vb2b, vb2b, vb2b};
  // bn per output dim (col)
  float sc0 = gamma[nl] * rsqrtf(var[nl] + BN_EPS);
  float sh0 = beta[nl] - mean[nl] * sc0;
  float sc1 = gamma[16 + nl] * rsqrtf(var[16 + nl] + BN_EPS);
  float sh1 = beta[16 + nl] - mean[16 + nl] * sc1;

  const int NW = gridDim.x * 4;
  for (int g = blockIdx.x * 4 + w; g < NGRP; g += NW) {
    int node = g * 16 + nl;
    int dcnt = cnt[node];
    if (dcnt > 63) dcnt = 63;
    int dE = dcnt + 1;  // edges + self (self at slot dcnt via b2 init)
    int dmax = __builtin_amdgcn_readfirstlane(gmax[g]);
    int nb = (dmax + 3) >> 2;   // >= 1 always

    const int* crow = csr + (size_t)node * MAXDEG;
    float acc[8];
#pragma unroll
    for (int i = 0; i < 8; ++i) acc[i] = 0.f;

    // pipeline prologue: idx(0) -> rows(0); idx(1)
    uint4 iA = *(const uint4*)crow;
    uint4 r0 = *(const uint4*)(hin16 + (size_t)iA.x * 32 + q * 8);
    uint4 r1 = *(const uint4*)(hin16 + (size_t)iA.y * 32 + q * 8);
    uint4 r2 = *(const uint4*)(hin16 + (size_t)iA.z * 32 + q * 8);
    uint4 r3 = *(const uint4*)(hin16 + (size_t)iA.w * 32 + q * 8);
    uint4 iB = iA;
    if (nb > 1) iB = *(const uint4*)(crow + 4);

    for (int b = 0; b < nb; ++b) {
      // issue rows(b+1) from iB, idx(b+2) into iC
      bool hasN = (b + 1 < nb);
      uint4 n0 = r0, n1 = r1, n2 = r2, n3 = r3;
      if (hasN) {
        n0 = *(const uint4*)(hin16 + (size_t)iB.x * 32 + q * 8);
        n1 = *(const uint4*)(hin16 + (size_t)iB.y * 32 + q * 8);
        n2 = *(const uint4*)(hin16 + (size_t)iB.z * 32 + q * 8);
        n3 = *(const uint4*)(hin16 + (size_t)iB.w * 32 + q * 8);
      }
      uint4 iC = iB;
      if (b + 2 < nb) iC = *(const uint4*)(crow + (b + 2) * 4);

      // accumulate batch b from r0..r3 (loads issued last iteration)
      int s0 = b * 4;
      if (s0 + 0 < dE) {
        acc[0] += bf_lo(r0.x); acc[1] += bf_hi(r0.x);
        acc[2] += bf_lo(r0.y); acc[3] += bf_hi(r0.y);
        acc[4] += bf_lo(r0.z); acc[5] += bf_hi(r0.z);
        acc[6] += bf_lo(r0.w); acc[7] += bf_hi(r0.w);
      }
      if (s0 + 1 < dE) {
        acc[0] += bf_lo(r1.x); acc[1] += bf_hi(r1.x);
        acc[2] += bf_lo(r1.y); acc[3] += bf_hi(r1.y);
        acc[4] += bf_lo(r1.z); acc[5] += bf_hi(r1.z);
        acc[6] += bf_lo(r1.w); acc[7] += bf_hi(r1.w);
      }
      if (s0 + 2 < dE) {
        acc[0] += bf_lo(r2.x); acc[1] += bf_hi(r2.x);
        acc[2] += bf_lo(r2.y); acc[3] += bf_hi(r2.y);
        acc[4] += bf_lo(r2.z); acc[5] += bf_hi(r2.z);
        acc[6] += bf_lo(r2.w); acc[7] += bf_hi(r2.w);
      }
      if (s0 + 3 < dE) {
        acc[0] += bf_lo(r3.x); acc[1] += bf_hi(r3.x);
        acc[2] += bf_lo(r3.y); acc[3] += bf_hi(r3.y);
        acc[4] += bf_lo(r3.z); acc[5] += bf_hi(r3.z);
        acc[6] += bf_lo(r3.w); acc[7] += bf_hi(r3.w);
      }
      // rotate
      r0 = n0; r1 = n1; r2 = n2; r3 = n3;
      iB = iC;
    }

    // ---- A fragment split hi/lo (layout matches accumulators exactly) ----
    bf16x8 af, afl;
#pragma unroll
    for (int i = 0; i < 8; ++i) {
      __bf16 h = (__bf16)acc[i];
      af[i] = h;
      afl[i] = (__bf16)(acc[i] - (float)h);
    }

    // ---- layer 1: T = relu(Z @ W1 + b1), 3 chained MFMAs per half ----
    f32x4 t0 = __builtin_amdgcn_mfma_f32_16x16x32_bf16(af,  w1ah, cb1a, 0, 0, 0);
    t0 = __builtin_amdgcn_mfma_f32_16x16x32_bf16(afl, w1ah, t0, 0, 0, 0);
    t0 = __builtin_amdgcn_mfma_f32_16x16x32_bf16(af,  w1al, t0, 0, 0, 0);
    f32x4 t1 = __builtin_amdgcn_mfma_f32_16x16x32_bf16(af,  w1bh, cb1b, 0, 0, 0);
    t1 = __builtin_amdgcn_mfma_f32_16x16x32_bf16(afl, w1bh, t1, 0, 0, 0);
    t1 = __builtin_amdgcn_mfma_f32_16x16x32_bf16(af,  w1bl, t1, 0, 0, 0);
#pragma unroll
    for (int r = 0; r < 4; ++r) {
      t0[r] = fmaxf(t0[r], 0.f);
      t1[r] = fmaxf(t1[r], 0.f);
    }
    // transpose D -> A2 via LDS (in-wave, DS ops are in-order within a wave)
#pragma unroll
    for (int r = 0; r < 4; ++r) {
      ts[w][q * 4 + r][nl]      = t0[r];
      ts[w][q * 4 + r][16 + nl] = t1[r];
    }
    bf16x8 af2, af2l;
    {
      float4 r0f = *(const float4*)&ts[w][nl][q * 8];
      float4 r1f = *(const float4*)&ts[w][nl][q * 8 + 4];
      float tv[8] = {r0f.x, r0f.y, r0f.z, r0f.w, r1f.x, r1f.y, r1f.z, r1f.w};
#pragma unroll
      for (int i = 0; i < 8; ++i) {
        __bf16 h = (__bf16)tv[i];
        af2[i] = h;
        af2l[i] = (__bf16)(tv[i] - (float)h);
      }
    }

    // ---- layer 2: O = bn(relu(T @ W2 + b2)), 3 chained MFMAs per half ----
    f32x4 o0 = __builtin_amdgcn_mfma_f32_16x16x32_bf16(af2,  w2ah, cb2a, 0, 0, 0);
    o0 = __builtin_amdgcn_mfma_f32_16x16x32_bf16(af2l, w2ah, o0, 0, 0, 0);
    o0 = __builtin_amdgcn_mfma_f32_16x16x32_bf16(af2,  w2al, o0, 0, 0, 0);
    f32x4 o1 = __builtin_amdgcn_mfma_f32_16x16x32_bf16(af2,  w2bh, cb2b, 0, 0, 0);
    o1 = __builtin_amdgcn_mfma_f32_16x16x32_bf16(af2l, w2bh, o1, 0, 0, 0);
    o1 = __builtin_amdgcn_mfma_f32_16x16x32_bf16(af2,  w2bl, o1, 0, 0, 0);
#pragma unroll
    for (int r = 0; r < 4; ++r) {
      o0[r] = fmaxf(o0[r], 0.f) * sc0 + sh0;
      o1[r] = fmaxf(o1[r], 0.f) * sc1 + sh1;
    }
    // transpose D -> row-major, pack bf16 pairs, coalesced uint4 store
#pragma unroll
    for (int r = 0; r < 4; ++r) {
      ts[w][q * 4 + r][nl]      = o0[r];
      ts[w][q * 4 + r][16 + nl] = o1[r];
    }
    {
      float4 f0 = *(const float4*)&ts[w][nl][q * 8];
      float4 f1 = *(const float4*)&ts[w][nl][q * 8 + 4];
      uint4 st;
      st.x = bf16_rne(f0.x) | (bf16_rne(f0.y) << 16);
      st.y = bf16_rne(f0.z) | (bf16_rne(f0.w) << 16);
      st.z = bf16_rne(f1.x) | (bf16_rne(f1.y) << 16);
      st.w = bf16_rne(f1.z) | (bf16_rne(f1.w) << 16);
      *(uint4*)(hout16 + (size_t)node * 32 + q * 8) = st;
    }
  }
}

// ---------------- pool: one block per graph (batch sorted), bf16 in ----------------
__global__ __launch_bounds__(256) void pool_kernel(const unsigned short* __restrict__ h16,
                                                   const int* __restrict__ batch,
                                                   float* __restrict__ g) {
  __shared__ int s_lo, s_hi;
  __shared__ float red[8][33];
  int gr = blockIdx.x;
  if (threadIdx.x == 0) {
    int lo = 0, hi = N_NODES;
    while (lo < hi) { int m = (lo + hi) >> 1; if (batch[m] < gr) lo = m + 1; else hi = m; }
    s_lo = lo;
  } else if (threadIdx.x == 1) {
    int lo = 0, hi = N_NODES;
    while (lo < hi) { int m = (lo + hi) >> 1; if (batch[m] < gr + 1) lo = m + 1; else hi = m; }
    s_hi = lo;
  }
  __syncthreads();
  int lo = s_lo, hi = s_hi;
  int j = threadIdx.x & 31;
  int nd = threadIdx.x >> 5;
  float acc = 0.f;
  for (int n = lo + nd; n < hi; n += 8)
    acc += __uint_as_float((unsigned)h16[n * 32 + j] << 16);
  red[nd][j] = acc;
  __syncthreads();
  if (threadIdx.x < 32) {
    float s = 0.f;
#pragma unroll
    for (int r = 0; r < 8; ++r) s += red[r][j];
    g[gr * 32 + j] = s;
  }
}

// ---------------- head (fp32) ----------------
__global__ __launch_bounds__(256) void head_kernel(
    const float* __restrict__ g, const float* __restrict__ W1, const float* __restrict__ b1,
    const float* __restrict__ W2, const float* __restrict__ b2, float* __restrict__ out) {
  __shared__ float sW1[1024], sb1[32];
  __shared__ float sW2[64], sb2[2];
  __shared__ float zb[8][33], tb[8][33], lb[8][2];
  int tid = threadIdx.x;
  for (int i = tid; i < 1024; i += 256) sW1[i] = W1[i];
  if (tid < 64) sW2[tid] = W2[tid];
  if (tid < 32) sb1[tid] = b1[tid];
  if (tid < 2) sb2[tid] = b2[tid];
  int nd = tid >> 5;
  int gr = blockIdx.x * 8 + nd;
  int j = tid & 31;
  __syncthreads();
  float z = (gr < N_GRAPHS) ? g[gr * 32 + j] : 0.f;
  zb[nd][j] = z;
  __syncthreads();
  float t = sb1[j];
#pragma unroll
  for (int k = 0; k < 32; ++k) t = fmaf(zb[nd][k], sW1[k * 32 + j], t);
  t = fmaxf(t, 0.f);
  tb[nd][j] = t;
  __syncthreads();
  if (j < 2) {
    float l = sb2[j];
#pragma unroll
    for (int k = 0; k < 32; ++k) l = fmaf(tb[nd][k], sW2[k * 2 + j], l);
    lb[nd][j] = l;
  }
  __syncthreads();
  if (gr < N_GRAPHS && j < 2) {
    float l0 = lb[nd][0], l1 = lb[nd][1];
    float m = fmaxf(l0, l1);
    float lse = m + logf(expf(l0 - m) + expf(l1 - m));
    out[gr * 2 + j] = lb[nd][j] - lse;
  }
}

extern "C" void kernel_launch(void* const* d_in, const int* in_sizes, int n_in,
                              void* d_out, int out_size, void* d_ws, size_t ws_size,
                              hipStream_t stream) {
  const float* x     = (const float*)d_in[0];
  const int*   eidx  = (const int*)d_in[1];
  const int*   batch = (const int*)d_in[2];
  const float* c1W1  = (const float*)d_in[3];
  const float* c1b1  = (const float*)d_in[4];
  const float* c1W2  = (const float*)d_in[5];
  const float* c1b2  = (const float*)d_in[6];
  const float* csW1  = (const float*)d_in[7];
  const float* csb1  = (const float*)d_in[8];
  const float* csW2  = (const float*)d_in[9];
  const float* csb2  = (const float*)d_in[10];
  const float* bng   = (const float*)d_in[11];
  const float* bnb   = (const float*)d_in[12];
  const float* bnm   = (const float*)d_in[13];
  const float* bnv   = (const float*)d_in[14];
  const float* fc1W  = (const float*)d_in[15];
  const float* fc1b  = (const float*)d_in[16];
  const float* fc2W  = (const float*)d_in[17];
  const float* fc2b  = (const float*)d_in[18];
  float* out = (float*)d_out;

  const int* src = eidx;
  const int* dst = eidx + N_EDGES;

  // workspace (~50.3 MB)
  char* p = (char*)d_ws;
  unsigned short* hA16 = (unsigned short*)p; p += (size_t)N_NODES * 32 * 2;   // 6.4 MB
  unsigned short* hB16 = (unsigned short*)p; p += (size_t)N_NODES * 32 * 2;   // 6.4 MB
  int*      cnt  = (int*)p;      p += (size_t)N_NODES * 4;                    // 0.4 MB
  int*      csr  = (int*)p;      p += (size_t)NBKT * 128 * MAXDEG * 4;        // 25.6 MB
  unsigned* ebuf = (unsigned*)p; p += (size_t)NBKT * BCAP * 4;                // 11.2 MB
  int*      gCur = (int*)p;      p += 1024 * 4;
  int*      gmax = (int*)p;      p += (size_t)(NBKT * 8) * 4;                 // 25 KB
  float*    g    = (float*)p;    p += (size_t)N_GRAPHS * 32 * 4;
  // xc (bf16 [N,8], 1.6 MB) aliases ebuf: ebuf is dead after b2_csr completes
  unsigned* xc = ebuf;

  // ---- build: bucket pass + per-bucket padded-CSR pass ----
  (void)hipMemsetAsync(gCur, 0, 1024 * 4, stream);
  b1_bucket<<<(N_EDGES + E_PER_BLK - 1) / E_PER_BLK, 1024, 0, stream>>>(src, dst, gCur, ebuf);
  b2_csr<<<NBKT, 512, 0, stream>>>(ebuf, gCur, cnt, csr, gmax);

  // ---- x -> bf16 padded rows (after b2: xc aliases ebuf) ----
  xcvt_kernel<<<(N_NODES * 4 + 255) / 256, 256, 0, stream>>>(x, xc);

  // ---- conv1 (7->32) + relu + bn0, transposed gather ----
  gin1<<<(NGRP + 3) / 4, 256, 0, stream>>>(
      (const unsigned short*)xc, cnt, csr, gmax, c1W1, c1b1, c1W2, c1b2,
      bng, bnb, bnm, bnv, hA16);

  // ---- conv2..5 (32->32) + relu + bn1..4, pipelined gather + split MFMA MLP ----
  unsigned short* cur = hA16;
  unsigned short* nxt = hB16;
  for (int i = 0; i < 4; ++i) {
    gin_layer32<<<(NGRP + 3) / 4, 256, 0, stream>>>(
        cur, cnt, csr, gmax,
        csW1 + (size_t)i * 1024, csb1 + (size_t)i * 32,
        csW2 + (size_t)i * 1024, csb2 + (size_t)i * 32,
        bng + (size_t)(i + 1) * 32, bnb + (size_t)(i + 1) * 32,
        bnm + (size_t)(i + 1) * 32, bnv + (size_t)(i + 1) * 32, nxt);
    unsigned short* tmp = cur; cur = nxt; nxt = tmp;
  }

  pool_kernel<<<N_GRAPHS, 256, 0, stream>>>(cur, batch, g);
  head_kernel<<<(N_GRAPHS + 7) / 8, 256, 0, stream>>>(g, fc1W, fc1b, fc2W, fc2b, out);
}

// Round 16
// 293.402 us; speedup vs baseline: 1.3029x; 1.0087x over previous
//
#include <hip/hip_runtime.h>

#define N_NODES  100000
#define N_EDGES  2000000
#define N_GRAPHS 1000
#define NFEAT    7
#define BN_EPS   1e-5f
#define MAXDEG   64    // in-degree ~ Poisson(20); P(max over 100k > 63) < 1e-9

#define BSH      7     // 128-node dst buckets
#define NBKT     782   // ceil(100000/128)
#define BCAP     3584  // per-bucket edge cap: mean 2560 + 20 sigma
#define E_PER_BLK 4096
#define NGRP     6250  // 100000/16 node groups

// bf16 helpers (storage only; arithmetic fp32 unless noted)
__device__ __forceinline__ unsigned bf16_rne(float f) {
  unsigned u = __float_as_uint(f);
  return (u + 0x7FFFu + ((u >> 16) & 1u)) >> 16;
}
__device__ __forceinline__ float bf_lo(unsigned u) { return __uint_as_float(u << 16); }
__device__ __forceinline__ float bf_hi(unsigned u) { return __uint_as_float(u & 0xFFFF0000u); }

// MFMA fragment types (gfx950)
typedef __bf16 bf16x8 __attribute__((ext_vector_type(8)));
typedef float  f32x4  __attribute__((ext_vector_type(4)));

// ---------------- b1: bucket edges by dst>>7, block-contiguous writes ----------------
__global__ __launch_bounds__(1024) void b1_bucket(const int* __restrict__ src,
                                                  const int* __restrict__ dst,
                                                  int* __restrict__ gCur,
                                                  unsigned* __restrict__ ebuf) {
  __shared__ int hist[NBKT], base[NBKT];
  int tid = threadIdx.x;
  for (int i = tid; i < NBKT; i += 1024) hist[i] = 0;
  __syncthreads();
  unsigned pk[4];
  int bo[4];
  int e0 = blockIdx.x * E_PER_BLK;
#pragma unroll
  for (int k = 0; k < 4; ++k) {
    int e = e0 + k * 1024 + tid;
    if (e < N_EDGES) {
      int d = dst[e], s = src[e];
      int b = d >> BSH;
      int off = atomicAdd(&hist[b], 1);
      pk[k] = ((unsigned)(d & 127) << 17) | (unsigned)s;
      bo[k] = (b << 17) | off;
    } else {
      bo[k] = -1;
    }
  }
  __syncthreads();
  for (int i = tid; i < NBKT; i += 1024)
    base[i] = hist[i] ? atomicAdd(&gCur[i], hist[i]) : 0;
  __syncthreads();
#pragma unroll
  for (int k = 0; k < 4; ++k) {
    if (bo[k] >= 0) {
      int b = bo[k] >> 17, off = bo[k] & 0x1FFFF;
      int p = base[b] + off;
      if (p < BCAP) ebuf[(size_t)b * BCAP + p] = pk[k];
    }
  }
}

// ---------------- b2: one block per bucket -> padded csr (pad=self) + cnt + gmax ----------------
__global__ __launch_bounds__(512) void b2_csr(const unsigned* __restrict__ ebuf,
                                              const int* __restrict__ gCnt,
                                              int* __restrict__ cnt,
                                              int* __restrict__ csr,
                                              int* __restrict__ gmax) {
  __shared__ int hist[128];
  __shared__ int stage[128 * MAXDEG];
  int b = blockIdx.x, tid = threadIdx.x;
  if (tid < 128) hist[tid] = 0;
  // init stage to self-node id: pad slots become valid self rows, and slot
  // cnt (first un-filled) supplies the GIN self term.
  for (int i = tid; i < 128 * MAXDEG; i += 512) stage[i] = (b << BSH) + (i >> 6);
  __syncthreads();
  int n = gCnt[b];
  if (n > BCAP) n = BCAP;
  const unsigned* eb = ebuf + (size_t)b * BCAP;
  for (int i = tid; i < n; i += 512) {
    unsigned pk = eb[i];
    int dloc = (int)(pk >> 17);
    int slot = atomicAdd(&hist[dloc], 1);
    if (slot < MAXDEG) stage[(dloc << 6) + slot] = (int)(pk & 0x1FFFFu);
  }
  __syncthreads();
  if (tid < 128) {
    int gnode = (b << BSH) + tid;
    if (gnode < N_NODES) cnt[gnode] = hist[tid];
  }
  if (tid < 8) {  // per-16-node-group max effective degree (dE = min(d,63)+1)
    int mx = 1;
#pragma unroll
    for (int k = 0; k < 16; ++k) {
      int d = hist[tid * 16 + k];
      if (d > 63) d = 63;
      if (d + 1 > mx) mx = d + 1;
    }
    gmax[(b << 3) + tid] = mx;
  }
  const int4* st4 = (const int4*)stage;
  int4* dst4 = (int4*)(csr + (size_t)b * (128 * MAXDEG));
  for (int i = tid; i < 128 * MAXDEG / 4; i += 512) dst4[i] = st4[i];
}

// ---------------- xcvt: x (fp32 [N,7]) -> xc (bf16 [N,8], pad dim7 = 0) ----------------
__global__ __launch_bounds__(256) void xcvt_kernel(const float* __restrict__ x,
                                                   unsigned* __restrict__ xc) {
  int i = blockIdx.x * 256 + threadIdx.x;
  if (i >= N_NODES * 4) return;
  int n = i >> 2, p = i & 3;
  float lo = x[n * 7 + 2 * p];
  float hi = (2 * p + 1 < 7) ? x[n * 7 + 2 * p + 1] : 0.f;
  xc[i] = bf16_rne(lo) | (bf16_rne(hi) << 16);
}

// ---------------- conv1 (7->32): pipelined gather + double-split MFMA MLP (R16) ----------------
// Same template as gin_layer32 (R14/R15, proven): K=8 layer-1 realized as
// 16x16x32 MFMA with A nonzero only in q==0 lanes (k=0..7) and W1 B-frag rows
// >=7 zeroed; layer 2 identical to gin_layer32's. Gather keeps the R10 4B-chunk
// layout (lane (nl,q) owns dims [2q,2q+1]) + R15 one-batch-deep pipeline; z is
// assembled into the A-frag via an in-wave LDS stage (same pattern as ts).
__global__ __launch_bounds__(256) void gin1(
    const unsigned short* __restrict__ xc16, const int* __restrict__ cnt,
    const int* __restrict__ csr, const int* __restrict__ gmax,
    const float* __restrict__ W1, const float* __restrict__ b1,
    const float* __restrict__ W2, const float* __restrict__ b2,
    const float* __restrict__ gamma, const float* __restrict__ beta,
    const float* __restrict__ mean, const float* __restrict__ var,
    unsigned short* __restrict__ hout16) {
  __shared__ __align__(16) float zs[4][16][12];   // z staging (stride 12)
  __shared__ __align__(16) float ts[4][16][36];   // transpose buffer
  int tid = threadIdx.x;
  int w = __builtin_amdgcn_readfirstlane(tid >> 6);
  int lane = tid & 63;
  int nl = lane & 15;    // node within group (A row / B,D col)
  int q  = lane >> 4;    // k-block (A) / row-block (D)

  // layer-1 B frags: rows k=8q+i; only q==0, i<7 nonzero (x dim7 pad = 0)
  bf16x8 w1ah, w1al, w1bh, w1bl;
#pragma unroll
  for (int i = 0; i < 8; ++i) {
    float fa = 0.f, fb = 0.f;
    if (q == 0 && i < 7) {
      fa = W1[i * 32 + nl];
      fb = W1[i * 32 + 16 + nl];
    }
    __bf16 ha = (__bf16)fa;
    w1ah[i] = ha; w1al[i] = (__bf16)(fa - (float)ha);
    __bf16 hb = (__bf16)fb;
    w1bh[i] = hb; w1bl[i] = (__bf16)(fb - (float)hb);
  }
  // layer-2 B frags split hi/lo (full 32x32)
  bf16x8 w2ah, w2al, w2bh, w2bl;
#pragma unroll
  for (int i = 0; i < 8; ++i) {
    float f;
    __bf16 h;
    f = W2[(q * 8 + i) * 32 + nl];       h = (__bf16)f;
    w2ah[i] = h; w2al[i] = (__bf16)(f - (float)h);
    f = W2[(q * 8 + i) * 32 + 16 + nl];  h = (__bf16)f;
    w2bh[i] = h; w2bl[i] = (__bf16)(f - (float)h);
  }
  float vb1a = b1[nl], vb1b = b1[16 + nl];
  float vb2a = b2[nl], vb2b = b2[16 + nl];
  f32x4 cb1a = {vb1a, vb1a, vb1a, vb1a};
  f32x4 cb1b = {vb1b, vb1b, vb1b, vb1b};
  f32x4 cb2a = {vb2a, vb2a, vb2a, vb2a};
  f32x4 cb2b = {vb2b, vb2b, vb2b, vb2b};
  float sc0 = gamma[nl] * rsqrtf(var[nl] + BN_EPS);
  float sh0 = beta[nl] - mean[nl] * sc0;
  float sc1 = gamma[16 + nl] * rsqrtf(var[16 + nl] + BN_EPS);
  float sh1 = beta[16 + nl] - mean[16 + nl] * sc1;

  const unsigned* xc32 = (const unsigned*)xc16;  // 4 x unsigned per 16-B row

  const int NW = gridDim.x * 4;
  for (int g = blockIdx.x * 4 + w; g < NGRP; g += NW) {
    int node = g * 16 + nl;
    int dcnt = cnt[node];
    if (dcnt > 63) dcnt = 63;
    int dE = dcnt + 1;  // edges + self (slot dcnt = self via b2 init)
    int dmax = __builtin_amdgcn_readfirstlane(gmax[g]);
    int nb = (dmax + 3) >> 2;   // >= 1 always

    const int* crow = csr + (size_t)node * MAXDEG;
    float a0 = 0.f, a1 = 0.f;

    // pipelined gather: rows one batch ahead, idx two ahead
    uint4 iA = *(const uint4*)crow;
    unsigned r0 = xc32[(size_t)iA.x * 4 + q];
    unsigned r1 = xc32[(size_t)iA.y * 4 + q];
    unsigned r2 = xc32[(size_t)iA.z * 4 + q];
    unsigned r3 = xc32[(size_t)iA.w * 4 + q];
    uint4 iB = iA;
    if (nb > 1) iB = *(const uint4*)(crow + 4);

    for (int b = 0; b < nb; ++b) {
      bool hasN = (b + 1 < nb);
      unsigned n0 = r0, n1 = r1, n2 = r2, n3 = r3;
      if (hasN) {
        n0 = xc32[(size_t)iB.x * 4 + q];
        n1 = xc32[(size_t)iB.y * 4 + q];
        n2 = xc32[(size_t)iB.z * 4 + q];
        n3 = xc32[(size_t)iB.w * 4 + q];
      }
      uint4 iC = iB;
      if (b + 2 < nb) iC = *(const uint4*)(crow + (b + 2) * 4);

      int s0 = b * 4;
      if (s0 + 0 < dE) { a0 += bf_lo(r0); a1 += bf_hi(r0); }
      if (s0 + 1 < dE) { a0 += bf_lo(r1); a1 += bf_hi(r1); }
      if (s0 + 2 < dE) { a0 += bf_lo(r2); a1 += bf_hi(r2); }
      if (s0 + 3 < dE) { a0 += bf_lo(r3); a1 += bf_hi(r3); }
      r0 = n0; r1 = n1; r2 = n2; r3 = n3;
      iB = iC;
    }

    // deposit z: lane (nl,q) owns dims [2q, 2q+1]
    {
      float2 z0 = {a0, a1};
      *(float2*)&zs[w][nl][q * 2] = z0;
    }
    // assemble A-frag: q==0 lanes read the full 8-dim row; others zero
    bf16x8 af, afl;
#pragma unroll
    for (int i = 0; i < 8; ++i) { af[i] = (__bf16)0.f; afl[i] = (__bf16)0.f; }
    if (q == 0) {
      float4 z0 = *(const float4*)&zs[w][nl][0];
      float4 z1 = *(const float4*)&zs[w][nl][4];
      float zv[8] = {z0.x, z0.y, z0.z, z0.w, z1.x, z1.y, z1.z, z1.w};
#pragma unroll
      for (int i = 0; i < 8; ++i) {
        __bf16 h = (__bf16)zv[i];
        af[i] = h;
        afl[i] = (__bf16)(zv[i] - (float)h);
      }
    }

    // ---- layer 1: T = relu(Z @ W1 + b1), 3 chained MFMAs per half ----
    f32x4 t0 = __builtin_amdgcn_mfma_f32_16x16x32_bf16(af,  w1ah, cb1a, 0, 0, 0);
    t0 = __builtin_amdgcn_mfma_f32_16x16x32_bf16(afl, w1ah, t0, 0, 0, 0);
    t0 = __builtin_amdgcn_mfma_f32_16x16x32_bf16(af,  w1al, t0, 0, 0, 0);
    f32x4 t1 = __builtin_amdgcn_mfma_f32_16x16x32_bf16(af,  w1bh, cb1b, 0, 0, 0);
    t1 = __builtin_amdgcn_mfma_f32_16x16x32_bf16(afl, w1bh, t1, 0, 0, 0);
    t1 = __builtin_amdgcn_mfma_f32_16x16x32_bf16(af,  w1bl, t1, 0, 0, 0);
#pragma unroll
    for (int r = 0; r < 4; ++r) {
      t0[r] = fmaxf(t0[r], 0.f);
      t1[r] = fmaxf(t1[r], 0.f);
    }
    // transpose D -> A2 via LDS (in-wave)
#pragma unroll
    for (int r = 0; r < 4; ++r) {
      ts[w][q * 4 + r][nl]      = t0[r];
      ts[w][q * 4 + r][16 + nl] = t1[r];
    }
    bf16x8 af2, af2l;
    {
      float4 r0f = *(const float4*)&ts[w][nl][q * 8];
      float4 r1f = *(const float4*)&ts[w][nl][q * 8 + 4];
      float tv[8] = {r0f.x, r0f.y, r0f.z, r0f.w, r1f.x, r1f.y, r1f.z, r1f.w};
#pragma unroll
      for (int i = 0; i < 8; ++i) {
        __bf16 h = (__bf16)tv[i];
        af2[i] = h;
        af2l[i] = (__bf16)(tv[i] - (float)h);
      }
    }

    // ---- layer 2: O = bn(relu(T @ W2 + b2)), 3 chained MFMAs per half ----
    f32x4 o0 = __builtin_amdgcn_mfma_f32_16x16x32_bf16(af2,  w2ah, cb2a, 0, 0, 0);
    o0 = __builtin_amdgcn_mfma_f32_16x16x32_bf16(af2l, w2ah, o0, 0, 0, 0);
    o0 = __builtin_amdgcn_mfma_f32_16x16x32_bf16(af2,  w2al, o0, 0, 0, 0);
    f32x4 o1 = __builtin_amdgcn_mfma_f32_16x16x32_bf16(af2,  w2bh, cb2b, 0, 0, 0);
    o1 = __builtin_amdgcn_mfma_f32_16x16x32_bf16(af2l, w2bh, o1, 0, 0, 0);
    o1 = __builtin_amdgcn_mfma_f32_16x16x32_bf16(af2,  w2bl, o1, 0, 0, 0);
#pragma unroll
    for (int r = 0; r < 4; ++r) {
      o0[r] = fmaxf(o0[r], 0.f) * sc0 + sh0;
      o1[r] = fmaxf(o1[r], 0.f) * sc1 + sh1;
    }
    // transpose D -> row-major, pack bf16 pairs, coalesced uint4 store
#pragma unroll
    for (int r = 0; r < 4; ++r) {
      ts[w][q * 4 + r][nl]      = o0[r];
      ts[w][q * 4 + r][16 + nl] = o1[r];
    }
    {
      float4 f0 = *(const float4*)&ts[w][nl][q * 8];
      float4 f1 = *(const float4*)&ts[w][nl][q * 8 + 4];
      uint4 st;
      st.x = bf16_rne(f0.x) | (bf16_rne(f0.y) << 16);
      st.y = bf16_rne(f0.z) | (bf16_rne(f0.w) << 16);
      st.z = bf16_rne(f1.x) | (bf16_rne(f1.y) << 16);
      st.w = bf16_rne(f1.z) | (bf16_rne(f1.w) << 16);
      *(uint4*)(hout16 + (size_t)node * 32 + q * 8) = st;
    }
  }
}

// ---------------- conv2..5: pipelined transposed gather + double-split MFMA MLP (R15, proven) ----------------
__global__ __launch_bounds__(256) void gin_layer32(
    const unsigned short* __restrict__ hin16, const int* __restrict__ cnt,
    const int* __restrict__ csr, const int* __restrict__ gmax,
    const float* __restrict__ W1, const float* __restrict__ b1,
    const float* __restrict__ W2, const float* __restrict__ b2,
    const float* __restrict__ gamma, const float* __restrict__ beta,
    const float* __restrict__ mean, const float* __restrict__ var,
    unsigned short* __restrict__ hout16) {
  __shared__ __align__(16) float ts[4][16][36];   // 9.2 KB transpose buffer
  int tid = threadIdx.x;
  int w = __builtin_amdgcn_readfirstlane(tid >> 6);  // wave id, force-scalar
  int lane = tid & 63;
  int nl = lane & 15;    // node within group (A row / B,D col)
  int q  = lane >> 4;    // k-block (A) / row-block (D)

  // B fragments split hi/lo: lane holds W[k=8q+i][col nl] and [col 16+nl]
  bf16x8 w1ah, w1al, w1bh, w1bl, w2ah, w2al, w2bh, w2bl;
#pragma unroll
  for (int i = 0; i < 8; ++i) {
    float f;
    __bf16 h;
    f = W1[(q * 8 + i) * 32 + nl];       h = (__bf16)f;
    w1ah[i] = h; w1al[i] = (__bf16)(f - (float)h);
    f = W1[(q * 8 + i) * 32 + 16 + nl];  h = (__bf16)f;
    w1bh[i] = h; w1bl[i] = (__bf16)(f - (float)h);
    f = W2[(q * 8 + i) * 32 + nl];       h = (__bf16)f;
    w2ah[i] = h; w2al[i] = (__bf16)(f - (float)h);
    f = W2[(q * 8 + i) * 32 + 16 + nl];  h = (__bf16)f;
    w2bh[i] = h; w2bl[i] = (__bf16)(f - (float)h);
  }
  // bias C-inits (bias depends only on col n = nl / 16+nl; same for all rows)
  float vb1a = b1[nl], vb1b = b1[16 + nl];
  float vb2a = b2[nl], vb2b = b2[16 + nl];
  f32x4 cb1a = {vb1a, vb1a, vb1a, vb1a};
  f32x4 cb1b = {vb1b, vb1b, vb1b, vb1b};
  f32x4 cb2a = {vb2a, vb2a, vb2a, vb2a};
  f32x4 cb2b = {vb2b, vb2b, vb2b, vb2b};
  // bn per output dim (col)
  float sc0 = gamma[nl] * rsqrtf(var[nl] + BN_EPS);
  float sh0 = beta[nl] - mean[nl] * sc0;
  float sc1 = gamma[16 + nl] * rsqrtf(var[16 + nl] + BN_EPS);
  float sh1 = beta[16 + nl] - mean[16 + nl] * sc1;

  const int NW = gridDim.x * 4;
  for (int g = blockIdx.x * 4 + w; g < NGRP; g += NW) {
    int node = g * 16 + nl;
    int dcnt = cnt[node];
    if (dcnt > 63) dcnt = 63;
    int dE = dcnt + 1;  // edges + self (self at slot dcnt via b2 init)
    int dmax = __builtin_amdgcn_readfirstlane(gmax[g]);
    int nb = (dmax + 3) >> 2;   // >= 1 always

    const int* crow = csr + (size_t)node * MAXDEG;
    float acc[8];
#pragma unroll
    for (int i = 0; i < 8; ++i) acc[i] = 0.f;

    // pipeline prologue: idx(0) -> rows(0); idx(1)
    uint4 iA = *(const uint4*)crow;
    uint4 r0 = *(const uint4*)(hin16 + (size_t)iA.x * 32 + q * 8);
    uint4 r1 = *(const uint4*)(hin16 + (size_t)iA.y * 32 + q * 8);
    uint4 r2 = *(const uint4*)(hin16 + (size_t)iA.z * 32 + q * 8);
    uint4 r3 = *(const uint4*)(hin16 + (size_t)iA.w * 32 + q * 8);
    uint4 iB = iA;
    if (nb > 1) iB = *(const uint4*)(crow + 4);

    for (int b = 0; b < nb; ++b) {
      // issue rows(b+1) from iB, idx(b+2) into iC
      bool hasN = (b + 1 < nb);
      uint4 n0 = r0, n1 = r1, n2 = r2, n3 = r3;
      if (hasN) {
        n0 = *(const uint4*)(hin16 + (size_t)iB.x * 32 + q * 8);
        n1 = *(const uint4*)(hin16 + (size_t)iB.y * 32 + q * 8);
        n2 = *(const uint4*)(hin16 + (size_t)iB.z * 32 + q * 8);
        n3 = *(const uint4*)(hin16 + (size_t)iB.w * 32 + q * 8);
      }
      uint4 iC = iB;
      if (b + 2 < nb) iC = *(const uint4*)(crow + (b + 2) * 4);

      // accumulate batch b from r0..r3 (loads issued last iteration)
      int s0 = b * 4;
      if (s0 + 0 < dE) {
        acc[0] += bf_lo(r0.x); acc[1] += bf_hi(r0.x);
        acc[2] += bf_lo(r0.y); acc[3] += bf_hi(r0.y);
        acc[4] += bf_lo(r0.z); acc[5] += bf_hi(r0.z);
        acc[6] += bf_lo(r0.w); acc[7] += bf_hi(r0.w);
      }
      if (s0 + 1 < dE) {
        acc[0] += bf_lo(r1.x); acc[1] += bf_hi(r1.x);
        acc[2] += bf_lo(r1.y); acc[3] += bf_hi(r1.y);
        acc[4] += bf_lo(r1.z); acc[5] += bf_hi(r1.z);
        acc[6] += bf_lo(r1.w); acc[7] += bf_hi(r1.w);
      }
      if (s0 + 2 < dE) {
        acc[0] += bf_lo(r2.x); acc[1] += bf_hi(r2.x);
        acc[2] += bf_lo(r2.y); acc[3] += bf_hi(r2.y);
        acc[4] += bf_lo(r2.z); acc[5] += bf_hi(r2.z);
        acc[6] += bf_lo(r2.w); acc[7] += bf_hi(r2.w);
      }
      if (s0 + 3 < dE) {
        acc[0] += bf_lo(r3.x); acc[1] += bf_hi(r3.x);
        acc[2] += bf_lo(r3.y); acc[3] += bf_hi(r3.y);
        acc[4] += bf_lo(r3.z); acc[5] += bf_hi(r3.z);
        acc[6] += bf_lo(r3.w); acc[7] += bf_hi(r3.w);
      }
      // rotate
      r0 = n0; r1 = n1; r2 = n2; r3 = n3;
      iB = iC;
    }

    // ---- A fragment split hi/lo (layout matches accumulators exactly) ----
    bf16x8 af, afl;
#pragma unroll
    for (int i = 0; i < 8; ++i) {
      __bf16 h = (__bf16)acc[i];
      af[i] = h;
      afl[i] = (__bf16)(acc[i] - (float)h);
    }

    // ---- layer 1: T = relu(Z @ W1 + b1), 3 chained MFMAs per half ----
    f32x4 t0 = __builtin_amdgcn_mfma_f32_16x16x32_bf16(af,  w1ah, cb1a, 0, 0, 0);
    t0 = __builtin_amdgcn_mfma_f32_16x16x32_bf16(afl, w1ah, t0, 0, 0, 0);
    t0 = __builtin_amdgcn_mfma_f32_16x16x32_bf16(af,  w1al, t0, 0, 0, 0);
    f32x4 t1 = __builtin_amdgcn_mfma_f32_16x16x32_bf16(af,  w1bh, cb1b, 0, 0, 0);
    t1 = __builtin_amdgcn_mfma_f32_16x16x32_bf16(afl, w1bh, t1, 0, 0, 0);
    t1 = __builtin_amdgcn_mfma_f32_16x16x32_bf16(af,  w1bl, t1, 0, 0, 0);
#pragma unroll
    for (int r = 0; r < 4; ++r) {
      t0[r] = fmaxf(t0[r], 0.f);
      t1[r] = fmaxf(t1[r], 0.f);
    }
    // transpose D -> A2 via LDS (in-wave, DS ops are in-order within a wave)
#pragma unroll
    for (int r = 0; r < 4; ++r) {
      ts[w][q * 4 + r][nl]      = t0[r];
      ts[w][q * 4 + r][16 + nl] = t1[r];
    }
    bf16x8 af2, af2l;
    {
      float4 r0f = *(const float4*)&ts[w][nl][q * 8];
      float4 r1f = *(const float4*)&ts[w][nl][q * 8 + 4];
      float tv[8] = {r0f.x, r0f.y, r0f.z, r0f.w, r1f.x, r1f.y, r1f.z, r1f.w};
#pragma unroll
      for (int i = 0; i < 8; ++i) {
        __bf16 h = (__bf16)tv[i];
        af2[i] = h;
        af2l[i] = (__bf16)(tv[i] - (float)h);
      }
    }

    // ---- layer 2: O = bn(relu(T @ W2 + b2)), 3 chained MFMAs per half ----
    f32x4 o0 = __builtin_amdgcn_mfma_f32_16x16x32_bf16(af2,  w2ah, cb2a, 0, 0, 0);
    o0 = __builtin_amdgcn_mfma_f32_16x16x32_bf16(af2l, w2ah, o0, 0, 0, 0);
    o0 = __builtin_amdgcn_mfma_f32_16x16x32_bf16(af2,  w2al, o0, 0, 0, 0);
    f32x4 o1 = __builtin_amdgcn_mfma_f32_16x16x32_bf16(af2,  w2bh, cb2b, 0, 0, 0);
    o1 = __builtin_amdgcn_mfma_f32_16x16x32_bf16(af2l, w2bh, o1, 0, 0, 0);
    o1 = __builtin_amdgcn_mfma_f32_16x16x32_bf16(af2,  w2bl, o1, 0, 0, 0);
#pragma unroll
    for (int r = 0; r < 4; ++r) {
      o0[r] = fmaxf(o0[r], 0.f) * sc0 + sh0;
      o1[r] = fmaxf(o1[r], 0.f) * sc1 + sh1;
    }
    // transpose D -> row-major, pack bf16 pairs, coalesced uint4 store
#pragma unroll
    for (int r = 0; r < 4; ++r) {
      ts[w][q * 4 + r][nl]      = o0[r];
      ts[w][q * 4 + r][16 + nl] = o1[r];
    }
    {
      float4 f0 = *(const float4*)&ts[w][nl][q * 8];
      float4 f1 = *(const float4*)&ts[w][nl][q * 8 + 4];
      uint4 st;
      st.x = bf16_rne(f0.x) | (bf16_rne(f0.y) << 16);
      st.y = bf16_rne(f0.z) | (bf16_rne(f0.w) << 16);
      st.z = bf16_rne(f1.x) | (bf16_rne(f1.y) << 16);
      st.w = bf16_rne(f1.z) | (bf16_rne(f1.w) << 16);
      *(uint4*)(hout16 + (size_t)node * 32 + q * 8) = st;
    }
  }
}

// ---------------- pool: one block per graph (batch sorted), bf16 in ----------------
__global__ __launch_bounds__(256) void pool_kernel(const unsigned short* __restrict__ h16,
                                                   const int* __restrict__ batch,
                                                   float* __restrict__ g) {
  __shared__ int s_lo, s_hi;
  __shared__ float red[8][33];
  int gr = blockIdx.x;
  if (threadIdx.x == 0) {
    int lo = 0, hi = N_NODES;
    while (lo < hi) { int m = (lo + hi) >> 1; if (batch[m] < gr) lo = m + 1; else hi = m; }
    s_lo = lo;
  } else if (threadIdx.x == 1) {
    int lo = 0, hi = N_NODES;
    while (lo < hi) { int m = (lo + hi) >> 1; if (batch[m] < gr + 1) lo = m + 1; else hi = m; }
    s_hi = lo;
  }
  __syncthreads();
  int lo = s_lo, hi = s_hi;
  int j = threadIdx.x & 31;
  int nd = threadIdx.x >> 5;
  float acc = 0.f;
  for (int n = lo + nd; n < hi; n += 8)
    acc += __uint_as_float((unsigned)h16[n * 32 + j] << 16);
  red[nd][j] = acc;
  __syncthreads();
  if (threadIdx.x < 32) {
    float s = 0.f;
#pragma unroll
    for (int r = 0; r < 8; ++r) s += red[r][j];
    g[gr * 32 + j] = s;
  }
}

// ---------------- head (fp32) ----------------
__global__ __launch_bounds__(256) void head_kernel(
    const float* __restrict__ g, const float* __restrict__ W1, const float* __restrict__ b1,
    const float* __restrict__ W2, const float* __restrict__ b2, float* __restrict__ out) {
  __shared__ float sW1[1024], sb1[32];
  __shared__ float sW2[64], sb2[2];
  __shared__ float zb[8][33], tb[8][33], lb[8][2];
  int tid = threadIdx.x;
  for (int i = tid; i < 1024; i += 256) sW1[i] = W1[i];
  if (tid < 64) sW2[tid] = W2[tid];
  if (tid < 32) sb1[tid] = b1[tid];
  if (tid < 2) sb2[tid] = b2[tid];
  int nd = tid >> 5;
  int gr = blockIdx.x * 8 + nd;
  int j = tid & 31;
  __syncthreads();
  float z = (gr < N_GRAPHS) ? g[gr * 32 + j] : 0.f;
  zb[nd][j] = z;
  __syncthreads();
  float t = sb1[j];
#pragma unroll
  for (int k = 0; k < 32; ++k) t = fmaf(zb[nd][k], sW1[k * 32 + j], t);
  t = fmaxf(t, 0.f);
  tb[nd][j] = t;
  __syncthreads();
  if (j < 2) {
    float l = sb2[j];
#pragma unroll
    for (int k = 0; k < 32; ++k) l = fmaf(tb[nd][k], sW2[k * 2 + j], l);
    lb[nd][j] = l;
  }
  __syncthreads();
  if (gr < N_GRAPHS && j < 2) {
    float l0 = lb[nd][0], l1 = lb[nd][1];
    float m = fmaxf(l0, l1);
    float lse = m + logf(expf(l0 - m) + expf(l1 - m));
    out[gr * 2 + j] = lb[nd][j] - lse;
  }
}

extern "C" void kernel_launch(void* const* d_in, const int* in_sizes, int n_in,
                              void* d_out, int out_size, void* d_ws, size_t ws_size,
                              hipStream_t stream) {
  const float* x     = (const float*)d_in[0];
  const int*   eidx  = (const int*)d_in[1];
  const int*   batch = (const int*)d_in[2];
  const float* c1W1  = (const float*)d_in[3];
  const float* c1b1  = (const float*)d_in[4];
  const float* c1W2  = (const float*)d_in[5];
  const float* c1b2  = (const float*)d_in[6];
  const float* csW1  = (const float*)d_in[7];
  const float* csb1  = (const float*)d_in[8];
  const float* csW2  = (const float*)d_in[9];
  const float* csb2  = (const float*)d_in[10];
  const float* bng   = (const float*)d_in[11];
  const float* bnb   = (const float*)d_in[12];
  const float* bnm   = (const float*)d_in[13];
  const float* bnv   = (const float*)d_in[14];
  const float* fc1W  = (const float*)d_in[15];
  const float* fc1b  = (const float*)d_in[16];
  const float* fc2W  = (const float*)d_in[17];
  const float* fc2b  = (const float*)d_in[18];
  float* out = (float*)d_out;

  const int* src = eidx;
  const int* dst = eidx + N_EDGES;

  // workspace (~50.3 MB)
  char* p = (char*)d_ws;
  unsigned short* hA16 = (unsigned short*)p; p += (size_t)N_NODES * 32 * 2;   // 6.4 MB
  unsigned short* hB16 = (unsigned short*)p; p += (size_t)N_NODES * 32 * 2;   // 6.4 MB
  int*      cnt  = (int*)p;      p += (size_t)N_NODES * 4;                    // 0.4 MB
  int*      csr  = (int*)p;      p += (size_t)NBKT * 128 * MAXDEG * 4;        // 25.6 MB
  unsigned* ebuf = (unsigned*)p; p += (size_t)NBKT * BCAP * 4;                // 11.2 MB
  int*      gCur = (int*)p;      p += 1024 * 4;
  int*      gmax = (int*)p;      p += (size_t)(NBKT * 8) * 4;                 // 25 KB
  float*    g    = (float*)p;    p += (size_t)N_GRAPHS * 32 * 4;
  // xc (bf16 [N,8], 1.6 MB) aliases ebuf: ebuf is dead after b2_csr completes
  unsigned* xc = ebuf;

  // ---- build: bucket pass + per-bucket padded-CSR pass ----
  (void)hipMemsetAsync(gCur, 0, 1024 * 4, stream);
  b1_bucket<<<(N_EDGES + E_PER_BLK - 1) / E_PER_BLK, 1024, 0, stream>>>(src, dst, gCur, ebuf);
  b2_csr<<<NBKT, 512, 0, stream>>>(ebuf, gCur, cnt, csr, gmax);

  // ---- x -> bf16 padded rows (after b2: xc aliases ebuf) ----
  xcvt_kernel<<<(N_NODES * 4 + 255) / 256, 256, 0, stream>>>(x, xc);

  // ---- conv1 (7->32) + relu + bn0, pipelined gather + split MFMA MLP ----
  gin1<<<(NGRP + 3) / 4, 256, 0, stream>>>(
      (const unsigned short*)xc, cnt, csr, gmax, c1W1, c1b1, c1W2, c1b2,
      bng, bnb, bnm, bnv, hA16);

  // ---- conv2..5 (32->32) + relu + bn1..4, pipelined gather + split MFMA MLP ----
  unsigned short* cur = hA16;
  unsigned short* nxt = hB16;
  for (int i = 0; i < 4; ++i) {
    gin_layer32<<<(NGRP + 3) / 4, 256, 0, stream>>>(
        cur, cnt, csr, gmax,
        csW1 + (size_t)i * 1024, csb1 + (size_t)i * 32,
        csW2 + (size_t)i * 1024, csb2 + (size_t)i * 32,
        bng + (size_t)(i + 1) * 32, bnb + (size_t)(i + 1) * 32,
        bnm + (size_t)(i + 1) * 32, bnv + (size_t)(i + 1) * 32, nxt);
    unsigned short* tmp = cur; cur = nxt; nxt = tmp;
  }

  pool_kernel<<<N_GRAPHS, 256, 0, stream>>>(cur, batch, g);
  head_kernel<<<(N_GRAPHS + 7) / 8, 256, 0, stream>>>(g, fc1W, fc1b, fc2W, fc2b, out);
}